// Round 1
// baseline (428.180 us; speedup 1.0000x reference)
//
#include <hip/hip_runtime.h>

// 2-layer GCN: h = relu(Anorm @ (x@W1) + b1); out = relu(Anorm @ (h@W2) + b2)
// Anorm = sym-normalized adjacency with self-loops (PyG GCNConv default).
// Strategy: device-built CSR (by dst) -> gather-based aggregation (no f32 atomics).

constexpr int IN_DIM = 512;
constexpr int HD1 = 128;
constexpr int HD2 = 64;

// ---------- degree / norm ----------
__global__ __launch_bounds__(256) void k_deg(const int* __restrict__ dst, int E,
                                             int* __restrict__ deg) {
    int e = blockIdx.x * 256 + threadIdx.x;
    if (e < E) atomicAdd(&deg[dst[e]], 1);
}

__global__ __launch_bounds__(256) void k_dinv(const int* __restrict__ deg,
                                              float* __restrict__ dinv, int N) {
    int i = blockIdx.x * 256 + threadIdx.x;
    if (i < N) dinv[i] = rsqrtf((float)(deg[i] + 1));  // +1 = self loop
}

// ---------- prefix scan (3-phase) for CSR rowptr ----------
__global__ __launch_bounds__(256) void k_blocksum(const int* __restrict__ deg, int N,
                                                  int* __restrict__ bsum) {
    __shared__ int s[256];
    int t = threadIdx.x;
    int i = blockIdx.x * 256 + t;
    s[t] = (i < N) ? deg[i] : 0;
    __syncthreads();
    for (int st = 128; st > 0; st >>= 1) {
        if (t < st) s[t] += s[t + st];
        __syncthreads();
    }
    if (t == 0) bsum[blockIdx.x] = s[0];
}

__global__ __launch_bounds__(1024) void k_scan_bsum(int* __restrict__ bsum, int nb) {
    __shared__ int s[1024];
    int t = threadIdx.x;
    s[t] = (t < nb) ? bsum[t] : 0;
    __syncthreads();
    for (int off = 1; off < 1024; off <<= 1) {
        int v = (t >= off) ? s[t - off] : 0;
        __syncthreads();
        s[t] += v;
        __syncthreads();
    }
    if (t < nb) bsum[t] = (t == 0) ? 0 : s[t - 1];  // exclusive
}

__global__ __launch_bounds__(256) void k_scan_final(const int* __restrict__ deg, int N,
                                                    const int* __restrict__ bsum,
                                                    int* __restrict__ rowptr) {
    __shared__ int s[256];
    int t = threadIdx.x;
    int i = blockIdx.x * 256 + t;
    int v = (i < N) ? deg[i] : 0;
    s[t] = v;
    __syncthreads();
    for (int off = 1; off < 256; off <<= 1) {
        int u = (t >= off) ? s[t - off] : 0;
        __syncthreads();
        s[t] += u;
        __syncthreads();
    }
    int incl = s[t] + bsum[blockIdx.x];
    if (i < N) rowptr[i] = incl - v;
    if (i == N - 1) rowptr[N] = incl;
}

__global__ __launch_bounds__(256) void k_fill(const int* __restrict__ src,
                                              const int* __restrict__ dst, int E,
                                              const int* __restrict__ rowptr,
                                              int* __restrict__ fill,
                                              int* __restrict__ col) {
    int e = blockIdx.x * 256 + threadIdx.x;
    if (e < E) {
        int d = dst[e];
        int pos = rowptr[d] + atomicAdd(&fill[d], 1);
        col[pos] = src[e];
    }
}

// ---------- GEMM1: [N,512] @ [512,128] -> [N,128], f32 LDS-tiled ----------
__global__ __launch_bounds__(256) void k_gemm1(const float* __restrict__ X,
                                               const float* __restrict__ W,
                                               float* __restrict__ H, int N) {
    __shared__ float As[64][36];    // 64 rows x 32 k (+pad)
    __shared__ float Bs[32][132];   // 32 k x 128 n (+pad)
    const int block_row = blockIdx.x * 64;
    const int tid = threadIdx.x;
    const int tx = tid & 15;   // col group: 8 cols each
    const int ty = tid >> 4;   // row group: 4 rows each

    float acc[4][8];
#pragma unroll
    for (int i = 0; i < 4; i++)
#pragma unroll
        for (int j = 0; j < 8; j++) acc[i][j] = 0.f;

    for (int k0 = 0; k0 < IN_DIM; k0 += 32) {
        {   // A tile: 2048 floats, 2 passes of float4/thread
            int r = tid >> 3;
            int kc = (tid & 7) * 4;
#pragma unroll
            for (int p = 0; p < 2; p++) {
                int row = r + p * 32;
                int grow = block_row + row;
                float4 v = make_float4(0.f, 0.f, 0.f, 0.f);
                if (grow < N) v = *(const float4*)&X[(size_t)grow * IN_DIM + k0 + kc];
                As[row][kc + 0] = v.x; As[row][kc + 1] = v.y;
                As[row][kc + 2] = v.z; As[row][kc + 3] = v.w;
            }
        }
        {   // B tile: 4096 floats, 4 passes of float4/thread
            int kr = tid >> 5;
            int nc = (tid & 31) * 4;
#pragma unroll
            for (int p = 0; p < 4; p++) {
                int kk = kr + p * 8;
                float4 v = *(const float4*)&W[(size_t)(k0 + kk) * HD1 + nc];
                Bs[kk][nc + 0] = v.x; Bs[kk][nc + 1] = v.y;
                Bs[kk][nc + 2] = v.z; Bs[kk][nc + 3] = v.w;
            }
        }
        __syncthreads();
#pragma unroll
        for (int kk = 0; kk < 32; kk++) {
            float a[4], b[8];
#pragma unroll
            for (int i = 0; i < 4; i++) a[i] = As[ty * 4 + i][kk];
#pragma unroll
            for (int j = 0; j < 8; j++) b[j] = Bs[kk][tx * 8 + j];
#pragma unroll
            for (int i = 0; i < 4; i++)
#pragma unroll
                for (int j = 0; j < 8; j++) acc[i][j] = fmaf(a[i], b[j], acc[i][j]);
        }
        __syncthreads();
    }
#pragma unroll
    for (int i = 0; i < 4; i++) {
        int grow = block_row + ty * 4 + i;
        if (grow < N) {
#pragma unroll
            for (int j = 0; j < 8; j += 4) {
                float4 v = make_float4(acc[i][j], acc[i][j + 1], acc[i][j + 2], acc[i][j + 3]);
                *(float4*)&H[(size_t)grow * HD1 + tx * 8 + j] = v;
            }
        }
    }
}

// ---------- gather layer1: agg = sum_j norm*h1[j], +b1, relu. wave/node ----------
__global__ __launch_bounds__(256) void k_gather1(const float* __restrict__ h,
                                                 const int* __restrict__ rowptr,
                                                 const int* __restrict__ col,
                                                 const float* __restrict__ dinv,
                                                 const float* __restrict__ bias,
                                                 float* __restrict__ out, int N) {
    int wave = (blockIdx.x * 256 + threadIdx.x) >> 6;
    int lane = threadIdx.x & 63;
    if (wave >= N) return;
    const int i = wave;
    const float di = dinv[i];
    float acc0 = h[(size_t)i * HD1 + lane] * (di * di);
    float acc1 = h[(size_t)i * HD1 + lane + 64] * (di * di);
    const int beg = rowptr[i], end = rowptr[i + 1];
    for (int p = beg; p < end; p++) {
        int j = col[p];
        float nrm = dinv[j] * di;
        acc0 = fmaf(h[(size_t)j * HD1 + lane], nrm, acc0);
        acc1 = fmaf(h[(size_t)j * HD1 + lane + 64], nrm, acc1);
    }
    out[(size_t)i * HD1 + lane]      = fmaxf(acc0 + bias[lane], 0.f);
    out[(size_t)i * HD1 + lane + 64] = fmaxf(acc1 + bias[lane + 64], 0.f);
}

// ---------- GEMM2: [N,128] @ [128,64] -> [N,64] ----------
__global__ __launch_bounds__(256) void k_gemm2(const float* __restrict__ A,
                                               const float* __restrict__ W,
                                               float* __restrict__ H, int N) {
    __shared__ float Ws[HD1][HD2 + 1];
    for (int idx = threadIdx.x; idx < HD1 * HD2; idx += 256) {
        int k = idx >> 6, n = idx & 63;
        Ws[k][n] = W[idx];
    }
    __syncthreads();
    const int tx = threadIdx.x & 63;
    const int ty = threadIdx.x >> 6;
    const int row0 = blockIdx.x * 64;
    for (int rr = 0; rr < 64; rr += 4) {
        int row = row0 + rr + ty;
        if (row < N) {
            const float* a = &A[(size_t)row * HD1];
            float acc = 0.f;
#pragma unroll
            for (int k = 0; k < HD1; k++) acc = fmaf(a[k], Ws[k][tx], acc);
            H[(size_t)row * HD2 + tx] = acc;
        }
    }
}

// ---------- gather layer2: wave/node, 64 cols ----------
__global__ __launch_bounds__(256) void k_gather2(const float* __restrict__ h,
                                                 const int* __restrict__ rowptr,
                                                 const int* __restrict__ col,
                                                 const float* __restrict__ dinv,
                                                 const float* __restrict__ bias,
                                                 float* __restrict__ out, int N) {
    int wave = (blockIdx.x * 256 + threadIdx.x) >> 6;
    int lane = threadIdx.x & 63;
    if (wave >= N) return;
    const int i = wave;
    const float di = dinv[i];
    float acc = h[(size_t)i * HD2 + lane] * (di * di);
    const int beg = rowptr[i], end = rowptr[i + 1];
    for (int p = beg; p < end; p++) {
        int j = col[p];
        acc = fmaf(h[(size_t)j * HD2 + lane], dinv[j] * di, acc);
    }
    out[(size_t)i * HD2 + lane] = fmaxf(acc + bias[lane], 0.f);
}

extern "C" void kernel_launch(void* const* d_in, const int* in_sizes, int n_in,
                              void* d_out, int out_size, void* d_ws, size_t ws_size,
                              hipStream_t stream) {
    const float* x  = (const float*)d_in[0];
    const int*   ei = (const int*)d_in[1];
    const float* W1 = (const float*)d_in[2];
    const float* b1 = (const float*)d_in[3];
    const float* W2 = (const float*)d_in[4];
    const float* b2 = (const float*)d_in[5];
    float* out = (float*)d_out;

    const int N = in_sizes[0] / IN_DIM;     // 50000
    const int E = in_sizes[1] / 2;          // 800000
    const int* src = ei;
    const int* dst = ei + E;

    // workspace layout (256B aligned)
    char* w = (char*)d_ws;
    size_t off = 0;
    auto alloc = [&](size_t bytes) -> void* {
        void* p = w + off;
        off = (off + bytes + 255) & ~(size_t)255;
        return p;
    };
    int*   deg    = (int*)alloc((size_t)N * 4);
    int*   fill   = (int*)alloc((size_t)N * 4);
    int*   rowptr = (int*)alloc((size_t)(N + 1) * 4);
    int*   bsum   = (int*)alloc(1024 * 4);
    int*   col    = (int*)alloc((size_t)E * 4);
    float* dinv   = (float*)alloc((size_t)N * 4);
    float* h1     = (float*)alloc((size_t)N * HD1 * 4);   // also reused for h2
    float* agg1   = (float*)alloc((size_t)N * HD1 * 4);
    float* h2     = h1;  // h1 dead after gather1; HD2 < HD1 so it fits

    hipMemsetAsync(deg, 0, (size_t)N * 4, stream);
    hipMemsetAsync(fill, 0, (size_t)N * 4, stream);

    const int nb = (N + 255) / 256;
    const int eb = (E + 255) / 256;

    k_deg<<<eb, 256, 0, stream>>>(dst, E, deg);
    k_dinv<<<nb, 256, 0, stream>>>(deg, dinv, N);
    k_blocksum<<<nb, 256, 0, stream>>>(deg, N, bsum);
    k_scan_bsum<<<1, 1024, 0, stream>>>(bsum, nb);
    k_scan_final<<<nb, 256, 0, stream>>>(deg, N, bsum, rowptr);
    k_fill<<<eb, 256, 0, stream>>>(src, dst, E, rowptr, fill, col);

    k_gemm1<<<(N + 63) / 64, 256, 0, stream>>>(x, W1, h1, N);
    k_gather1<<<(N * 64 + 255) / 256, 256, 0, stream>>>(h1, rowptr, col, dinv, b1, agg1, N);
    k_gemm2<<<(N + 63) / 64, 256, 0, stream>>>(agg1, W2, h2, N);
    k_gather2<<<(N * 64 + 255) / 256, 256, 0, stream>>>(h2, rowptr, col, dinv, b2, out, N);
}

// Round 2
// 344.734 us; speedup vs baseline: 1.2421x; 1.2421x over previous
//
#include <hip/hip_runtime.h>

// 2-layer GCN: h = relu(Anorm @ (x@W1) + b1); out = relu(Anorm @ (h@W2) + b2)
// Round 1: GEMM1 -> bf16 MFMA (16x16x32), fused f32->bf16 conversion, h1 in bf16.

constexpr int IN_DIM = 512;
constexpr int HD1 = 128;
constexpr int HD2 = 64;

typedef __attribute__((ext_vector_type(8))) short bf16x8;
typedef __attribute__((ext_vector_type(8))) unsigned short u16x8;
typedef __attribute__((ext_vector_type(4))) float f32x4;
typedef unsigned int u32;

__device__ inline unsigned short f2bf(float f) {
    u32 u = __builtin_bit_cast(u32, f);
    return (unsigned short)((u + 0x7fffu + ((u >> 16) & 1u)) >> 16);
}
__device__ inline float bf_lo(u32 v) { return __builtin_bit_cast(float, v << 16); }
__device__ inline float bf_hi(u32 v) { return __builtin_bit_cast(float, v & 0xffff0000u); }

// swizzled LDS element offset for [row][64k] bf16 tiles (T2: spread banks)
__device__ inline int elem_off(int row, int k) {
    return (row << 6) + (k ^ ((row & 7) << 3));
}

// ---------- degree / norm ----------
__global__ __launch_bounds__(256) void k_deg(const int* __restrict__ dst, int E,
                                             int* __restrict__ deg) {
    int e = blockIdx.x * 256 + threadIdx.x;
    if (e < E) atomicAdd(&deg[dst[e]], 1);
}

__global__ __launch_bounds__(256) void k_dinv(const int* __restrict__ deg,
                                              float* __restrict__ dinv, int N) {
    int i = blockIdx.x * 256 + threadIdx.x;
    if (i < N) dinv[i] = rsqrtf((float)(deg[i] + 1));  // +1 = self loop
}

// ---------- prefix scan (3-phase) for CSR rowptr ----------
__global__ __launch_bounds__(256) void k_blocksum(const int* __restrict__ deg, int N,
                                                  int* __restrict__ bsum) {
    __shared__ int s[256];
    int t = threadIdx.x;
    int i = blockIdx.x * 256 + t;
    s[t] = (i < N) ? deg[i] : 0;
    __syncthreads();
    for (int st = 128; st > 0; st >>= 1) {
        if (t < st) s[t] += s[t + st];
        __syncthreads();
    }
    if (t == 0) bsum[blockIdx.x] = s[0];
}

__global__ __launch_bounds__(1024) void k_scan_bsum(int* __restrict__ bsum, int nb) {
    __shared__ int s[1024];
    int t = threadIdx.x;
    s[t] = (t < nb) ? bsum[t] : 0;
    __syncthreads();
    for (int off = 1; off < 1024; off <<= 1) {
        int v = (t >= off) ? s[t - off] : 0;
        __syncthreads();
        s[t] += v;
        __syncthreads();
    }
    if (t < nb) bsum[t] = (t == 0) ? 0 : s[t - 1];  // exclusive
}

__global__ __launch_bounds__(256) void k_scan_final(const int* __restrict__ deg, int N,
                                                    const int* __restrict__ bsum,
                                                    int* __restrict__ rowptr) {
    __shared__ int s[256];
    int t = threadIdx.x;
    int i = blockIdx.x * 256 + t;
    int v = (i < N) ? deg[i] : 0;
    s[t] = v;
    __syncthreads();
    for (int off = 1; off < 256; off <<= 1) {
        int u = (t >= off) ? s[t - off] : 0;
        __syncthreads();
        s[t] += u;
        __syncthreads();
    }
    int incl = s[t] + bsum[blockIdx.x];
    if (i < N) rowptr[i] = incl - v;
    if (i == N - 1) rowptr[N] = incl;
}

__global__ __launch_bounds__(256) void k_fill(const int* __restrict__ src,
                                              const int* __restrict__ dst, int E,
                                              const int* __restrict__ rowptr,
                                              int* __restrict__ fill,
                                              int* __restrict__ col) {
    int e = blockIdx.x * 256 + threadIdx.x;
    if (e < E) {
        int d = dst[e];
        int pos = rowptr[d] + atomicAdd(&fill[d], 1);
        col[pos] = src[e];
    }
}

// ---------- W1 -> bf16 transposed: Wt[n][k], n=0..127, k=0..511 ----------
__global__ __launch_bounds__(256) void k_wt(const float* __restrict__ W1,
                                            unsigned short* __restrict__ Wt) {
    int id = blockIdx.x * 256 + threadIdx.x;   // 65536
    int n = id >> 9, k = id & 511;
    Wt[id] = f2bf(W1[k * HD1 + n]);
}

// ---------- GEMM1: [N,512]f32 @ Wt[128][512]bf16 -> h1 [N,128]bf16, MFMA ----------
__global__ __launch_bounds__(256) void k_gemm1(const float* __restrict__ X,
                                               const unsigned short* __restrict__ Wt,
                                               unsigned short* __restrict__ H, int N) {
    __shared__ unsigned short As[128 * 64];  // x tile, swizzled [row][k]
    __shared__ unsigned short Bs[128 * 64];  // W tile, swizzled [col][k]

    const int tid = threadIdx.x;
    const int lane = tid & 63;
    const int wid = tid >> 6;
    const int brow = blockIdx.x * 128;
    const int wr0 = (wid >> 1) * 64;
    const int wc0 = (wid & 1) * 64;

    f32x4 acc[4][4];
#pragma unroll
    for (int i = 0; i < 4; i++)
#pragma unroll
        for (int j = 0; j < 4; j++) acc[i][j] = (f32x4){0.f, 0.f, 0.f, 0.f};

    for (int kt = 0; kt < IN_DIM / 64; kt++) {
        const int k0 = kt * 64;
        // ---- stage A: 128 rows x 64 k, f32 -> bf16, reg-staged ----
#pragma unroll
        for (int p = 0; p < 4; p++) {
            int chunk = tid + p * 256;     // 1024 chunks of 8 elems
            int r = chunk >> 3;
            int kc = chunk & 7;
            int grow = brow + r;
            float4 v0 = make_float4(0.f, 0.f, 0.f, 0.f), v1 = v0;
            if (grow < N) {
                const float* xp = &X[(size_t)grow * IN_DIM + k0 + kc * 8];
                v0 = *(const float4*)xp;
                v1 = *(const float4*)(xp + 4);
            }
            u16x8 w;
            w[0] = f2bf(v0.x); w[1] = f2bf(v0.y); w[2] = f2bf(v0.z); w[3] = f2bf(v0.w);
            w[4] = f2bf(v1.x); w[5] = f2bf(v1.y); w[6] = f2bf(v1.z); w[7] = f2bf(v1.w);
            *(u16x8*)&As[elem_off(r, kc * 8)] = w;
        }
        // ---- stage B: global_load_lds from pre-transposed Wt, pre-swizzled src ----
#pragma unroll
        for (int p = 0; p < 4; p++) {
            int chunk = (wid * 4 + p) * 64 + lane;  // 16B chunk id
            int n = chunk >> 3;
            int kcs = chunk & 7;
            int kc = kcs ^ (n & 7);                 // inverse swizzle on source
            const unsigned short* src = &Wt[(size_t)n * IN_DIM + k0 + kc * 8];
            unsigned short* dst = &Bs[(wid * 4 + p) * 512];  // wave-uniform base
            __builtin_amdgcn_global_load_lds(
                (const __attribute__((address_space(1))) u32*)(const void*)src,
                (__attribute__((address_space(3))) u32*)(void*)dst, 16, 0, 0);
        }
        __syncthreads();  // drains lgkmcnt (A writes) + vmcnt (B gload_lds)

#pragma unroll
        for (int kk = 0; kk < 2; kk++) {
            const int kel = kk * 32 + (lane >> 4) * 8;
            bf16x8 a[4], b[4];
#pragma unroll
            for (int mi = 0; mi < 4; mi++)
                a[mi] = *(const bf16x8*)&As[elem_off(wr0 + mi * 16 + (lane & 15), kel)];
#pragma unroll
            for (int ni = 0; ni < 4; ni++)
                b[ni] = *(const bf16x8*)&Bs[elem_off(wc0 + ni * 16 + (lane & 15), kel)];
#pragma unroll
            for (int mi = 0; mi < 4; mi++)
#pragma unroll
                for (int ni = 0; ni < 4; ni++)
                    acc[mi][ni] = __builtin_amdgcn_mfma_f32_16x16x32_bf16(
                        a[mi], b[ni], acc[mi][ni], 0, 0, 0);
        }
        __syncthreads();
    }

    // ---- store h1 as bf16: D layout col=lane&15, row=(lane>>4)*4+reg ----
#pragma unroll
    for (int mi = 0; mi < 4; mi++) {
#pragma unroll
        for (int reg = 0; reg < 4; reg++) {
            int grow = brow + wr0 + mi * 16 + (lane >> 4) * 4 + reg;
            if (grow < N) {
#pragma unroll
                for (int ni = 0; ni < 4; ni++) {
                    int gcol = wc0 + ni * 16 + (lane & 15);
                    H[(size_t)grow * HD1 + gcol] = f2bf(acc[mi][ni][reg]);
                }
            }
        }
    }
}

// ---------- gather layer1: bf16 h, f32 accumulate, +b1, relu -> f32 agg ----------
__global__ __launch_bounds__(256) void k_gather1(const unsigned short* __restrict__ h,
                                                 const int* __restrict__ rowptr,
                                                 const int* __restrict__ col,
                                                 const float* __restrict__ dinv,
                                                 const float* __restrict__ bias,
                                                 float* __restrict__ out, int N) {
    int wave = (blockIdx.x * 256 + threadIdx.x) >> 6;
    int lane = threadIdx.x & 63;
    if (wave >= N) return;
    const int i = wave;
    const float di = dinv[i];
    const float s = di * di;
    u32 hv = *(const u32*)&h[(size_t)i * HD1 + 2 * lane];
    float a0 = bf_lo(hv) * s;
    float a1 = bf_hi(hv) * s;
    const int beg = rowptr[i], end = rowptr[i + 1];
    for (int p = beg; p < end; p++) {
        int j = col[p];
        float nw = dinv[j] * di;
        u32 v = *(const u32*)&h[(size_t)j * HD1 + 2 * lane];
        a0 = fmaf(bf_lo(v), nw, a0);
        a1 = fmaf(bf_hi(v), nw, a1);
    }
    float2 bv = *(const float2*)&bias[2 * lane];
    float2 r = make_float2(fmaxf(a0 + bv.x, 0.f), fmaxf(a1 + bv.y, 0.f));
    *(float2*)&out[(size_t)i * HD1 + 2 * lane] = r;
}

// ---------- GEMM2: [N,128]f32 @ [128,64] -> [N,64] f32 ----------
__global__ __launch_bounds__(256) void k_gemm2(const float* __restrict__ A,
                                               const float* __restrict__ W,
                                               float* __restrict__ H, int N) {
    __shared__ float Ws[HD1][HD2 + 1];
    for (int idx = threadIdx.x; idx < HD1 * HD2; idx += 256) {
        int k = idx >> 6, n = idx & 63;
        Ws[k][n] = W[idx];
    }
    __syncthreads();
    const int tx = threadIdx.x & 63;
    const int ty = threadIdx.x >> 6;
    const int row0 = blockIdx.x * 64;
    for (int rr = 0; rr < 64; rr += 4) {
        int row = row0 + rr + ty;
        if (row < N) {
            const float* a = &A[(size_t)row * HD1];
            float acc = 0.f;
#pragma unroll
            for (int k = 0; k < HD1; k++) acc = fmaf(a[k], Ws[k][tx], acc);
            H[(size_t)row * HD2 + tx] = acc;
        }
    }
}

// ---------- gather layer2: wave/node, 64 cols ----------
__global__ __launch_bounds__(256) void k_gather2(const float* __restrict__ h,
                                                 const int* __restrict__ rowptr,
                                                 const int* __restrict__ col,
                                                 const float* __restrict__ dinv,
                                                 const float* __restrict__ bias,
                                                 float* __restrict__ out, int N) {
    int wave = (blockIdx.x * 256 + threadIdx.x) >> 6;
    int lane = threadIdx.x & 63;
    if (wave >= N) return;
    const int i = wave;
    const float di = dinv[i];
    float acc = h[(size_t)i * HD2 + lane] * (di * di);
    const int beg = rowptr[i], end = rowptr[i + 1];
    for (int p = beg; p < end; p++) {
        int j = col[p];
        acc = fmaf(h[(size_t)j * HD2 + lane], dinv[j] * di, acc);
    }
    out[(size_t)i * HD2 + lane] = fmaxf(acc + bias[lane], 0.f);
}

extern "C" void kernel_launch(void* const* d_in, const int* in_sizes, int n_in,
                              void* d_out, int out_size, void* d_ws, size_t ws_size,
                              hipStream_t stream) {
    const float* x  = (const float*)d_in[0];
    const int*   ei = (const int*)d_in[1];
    const float* W1 = (const float*)d_in[2];
    const float* b1 = (const float*)d_in[3];
    const float* W2 = (const float*)d_in[4];
    const float* b2 = (const float*)d_in[5];
    float* out = (float*)d_out;

    const int N = in_sizes[0] / IN_DIM;     // 50000
    const int E = in_sizes[1] / 2;          // 800000
    const int* src = ei;
    const int* dst = ei + E;

    // workspace layout (256B aligned)
    char* w = (char*)d_ws;
    size_t off = 0;
    auto alloc = [&](size_t bytes) -> void* {
        void* p = w + off;
        off = (off + bytes + 255) & ~(size_t)255;
        return p;
    };
    int*   deg    = (int*)alloc((size_t)N * 4);
    int*   fill   = (int*)alloc((size_t)N * 4);
    int*   rowptr = (int*)alloc((size_t)(N + 1) * 4);
    int*   bsum   = (int*)alloc(1024 * 4);
    int*   col    = (int*)alloc((size_t)E * 4);
    float* dinv   = (float*)alloc((size_t)N * 4);
    unsigned short* Wt = (unsigned short*)alloc((size_t)IN_DIM * HD1 * 2);
    unsigned short* h1 = (unsigned short*)alloc((size_t)N * HD1 * 2);  // bf16
    float* agg1   = (float*)alloc((size_t)N * HD1 * 4);
    float* h2     = (float*)h1;  // 50000*64*4 == 50000*128*2, exact reuse

    hipMemsetAsync(deg, 0, (size_t)N * 4, stream);
    hipMemsetAsync(fill, 0, (size_t)N * 4, stream);

    const int nb = (N + 255) / 256;
    const int eb = (E + 255) / 256;

    k_deg<<<eb, 256, 0, stream>>>(dst, E, deg);
    k_dinv<<<nb, 256, 0, stream>>>(deg, dinv, N);
    k_blocksum<<<nb, 256, 0, stream>>>(deg, N, bsum);
    k_scan_bsum<<<1, 1024, 0, stream>>>(bsum, nb);
    k_scan_final<<<nb, 256, 0, stream>>>(deg, N, bsum, rowptr);
    k_fill<<<eb, 256, 0, stream>>>(src, dst, E, rowptr, fill, col);
    k_wt<<<IN_DIM * HD1 / 256, 256, 0, stream>>>(W1, Wt);

    k_gemm1<<<(N + 127) / 128, 256, 0, stream>>>(x, Wt, h1, N);
    k_gather1<<<(N * 64 + 255) / 256, 256, 0, stream>>>(h1, rowptr, col, dinv, b1, agg1, N);
    k_gemm2<<<(N + 63) / 64, 256, 0, stream>>>(agg1, W2, h2, N);
    k_gather2<<<(N * 64 + 255) / 256, 256, 0, stream>>>(h2, rowptr, col, dinv, b2, out, N);
}

// Round 3
// 192.509 us; speedup vs baseline: 2.2242x; 1.7907x over previous
//
#include <hip/hip_runtime.h>

// 2-layer GCN: h = relu(Anorm @ (x@W1) + b1); out = relu(Anorm @ (h@W2) + b2)
// Round 2: high-MLP gathers (shfl-broadcast cols, 4 gathers in flight, precomputed
// edge weights), agg1/h2 in bf16, GEMM2 -> bf16 MFMA.

constexpr int IN_DIM = 512;
constexpr int HD1 = 128;
constexpr int HD2 = 64;

typedef __attribute__((ext_vector_type(8))) short bf16x8;
typedef __attribute__((ext_vector_type(8))) unsigned short u16x8;
typedef __attribute__((ext_vector_type(4))) float f32x4;
typedef unsigned int u32;

__device__ inline unsigned short f2bf(float f) {
    u32 u = __builtin_bit_cast(u32, f);
    return (unsigned short)((u + 0x7fffu + ((u >> 16) & 1u)) >> 16);
}
__device__ inline float bf_lo(u32 v) { return __builtin_bit_cast(float, v << 16); }
__device__ inline float bf_hi(u32 v) { return __builtin_bit_cast(float, v & 0xffff0000u); }

// swizzled LDS element offset, [row][64] bf16 tiles
__device__ inline int elem_off(int row, int k) {
    return (row << 6) + (k ^ ((row & 7) << 3));
}
// swizzled LDS element offset, [row][128] bf16 tiles
__device__ inline int elem_off128(int row, int k) {
    return (row << 7) + (k ^ ((row & 7) << 3));
}

// ---------- degree / norm ----------
__global__ __launch_bounds__(256) void k_deg(const int* __restrict__ dst, int E,
                                             int* __restrict__ deg) {
    int e = blockIdx.x * 256 + threadIdx.x;
    if (e < E) atomicAdd(&deg[dst[e]], 1);
}

__global__ __launch_bounds__(256) void k_dinv(const int* __restrict__ deg,
                                              float* __restrict__ dinv, int N) {
    int i = blockIdx.x * 256 + threadIdx.x;
    if (i < N) dinv[i] = rsqrtf((float)(deg[i] + 1));  // +1 = self loop
}

// ---------- prefix scan (3-phase) for CSR rowptr ----------
__global__ __launch_bounds__(256) void k_blocksum(const int* __restrict__ deg, int N,
                                                  int* __restrict__ bsum) {
    __shared__ int s[256];
    int t = threadIdx.x;
    int i = blockIdx.x * 256 + t;
    s[t] = (i < N) ? deg[i] : 0;
    __syncthreads();
    for (int st = 128; st > 0; st >>= 1) {
        if (t < st) s[t] += s[t + st];
        __syncthreads();
    }
    if (t == 0) bsum[blockIdx.x] = s[0];
}

__global__ __launch_bounds__(1024) void k_scan_bsum(int* __restrict__ bsum, int nb) {
    __shared__ int s[1024];
    int t = threadIdx.x;
    s[t] = (t < nb) ? bsum[t] : 0;
    __syncthreads();
    for (int off = 1; off < 1024; off <<= 1) {
        int v = (t >= off) ? s[t - off] : 0;
        __syncthreads();
        s[t] += v;
        __syncthreads();
    }
    if (t < nb) bsum[t] = (t == 0) ? 0 : s[t - 1];  // exclusive
}

__global__ __launch_bounds__(256) void k_scan_final(const int* __restrict__ deg, int N,
                                                    const int* __restrict__ bsum,
                                                    int* __restrict__ rowptr) {
    __shared__ int s[256];
    int t = threadIdx.x;
    int i = blockIdx.x * 256 + t;
    int v = (i < N) ? deg[i] : 0;
    s[t] = v;
    __syncthreads();
    for (int off = 1; off < 256; off <<= 1) {
        int u = (t >= off) ? s[t - off] : 0;
        __syncthreads();
        s[t] += u;
        __syncthreads();
    }
    int incl = s[t] + bsum[blockIdx.x];
    if (i < N) rowptr[i] = incl - v;
    if (i == N - 1) rowptr[N] = incl;
}

__global__ __launch_bounds__(256) void k_fill(const int* __restrict__ src,
                                              const int* __restrict__ dst, int E,
                                              const int* __restrict__ rowptr,
                                              const float* __restrict__ dinv,
                                              int* __restrict__ fill,
                                              int* __restrict__ col,
                                              float* __restrict__ wgt) {
    int e = blockIdx.x * 256 + threadIdx.x;
    if (e < E) {
        int s = src[e], d = dst[e];
        int pos = rowptr[d] + atomicAdd(&fill[d], 1);
        col[pos] = s;
        wgt[pos] = dinv[s] * dinv[d];
    }
}

// ---------- weight transposes -> bf16 ----------
__global__ __launch_bounds__(256) void k_wt(const float* __restrict__ W1,
                                            unsigned short* __restrict__ Wt) {
    int id = blockIdx.x * 256 + threadIdx.x;   // 65536
    int n = id >> 9, k = id & 511;
    Wt[id] = f2bf(W1[k * HD1 + n]);
}

__global__ __launch_bounds__(256) void k_wt2(const float* __restrict__ W2,
                                             unsigned short* __restrict__ Wt2) {
    int id = blockIdx.x * 256 + threadIdx.x;   // 8192
    int n = id >> 7, k = id & 127;
    Wt2[id] = f2bf(W2[k * HD2 + n]);
}

// ---------- GEMM1: [N,512]f32 @ Wt[128][512]bf16 -> h1 [N,128]bf16, MFMA ----------
__global__ __launch_bounds__(256) void k_gemm1(const float* __restrict__ X,
                                               const unsigned short* __restrict__ Wt,
                                               unsigned short* __restrict__ H, int N) {
    __shared__ unsigned short As[128 * 64];  // x tile, swizzled [row][k]
    __shared__ unsigned short Bs[128 * 64];  // W tile, swizzled [col][k]

    const int tid = threadIdx.x;
    const int lane = tid & 63;
    const int wid = tid >> 6;
    const int brow = blockIdx.x * 128;
    const int wr0 = (wid >> 1) * 64;
    const int wc0 = (wid & 1) * 64;

    f32x4 acc[4][4];
#pragma unroll
    for (int i = 0; i < 4; i++)
#pragma unroll
        for (int j = 0; j < 4; j++) acc[i][j] = (f32x4){0.f, 0.f, 0.f, 0.f};

    for (int kt = 0; kt < IN_DIM / 64; kt++) {
        const int k0 = kt * 64;
        // ---- stage A: 128 rows x 64 k, f32 -> bf16, reg-staged ----
#pragma unroll
        for (int p = 0; p < 4; p++) {
            int chunk = tid + p * 256;     // 1024 chunks of 8 elems
            int r = chunk >> 3;
            int kc = chunk & 7;
            int grow = brow + r;
            float4 v0 = make_float4(0.f, 0.f, 0.f, 0.f), v1 = v0;
            if (grow < N) {
                const float* xp = &X[(size_t)grow * IN_DIM + k0 + kc * 8];
                v0 = *(const float4*)xp;
                v1 = *(const float4*)(xp + 4);
            }
            u16x8 w;
            w[0] = f2bf(v0.x); w[1] = f2bf(v0.y); w[2] = f2bf(v0.z); w[3] = f2bf(v0.w);
            w[4] = f2bf(v1.x); w[5] = f2bf(v1.y); w[6] = f2bf(v1.z); w[7] = f2bf(v1.w);
            *(u16x8*)&As[elem_off(r, kc * 8)] = w;
        }
        // ---- stage B: global_load_lds from pre-transposed Wt, pre-swizzled src ----
#pragma unroll
        for (int p = 0; p < 4; p++) {
            int chunk = (wid * 4 + p) * 64 + lane;  // 16B chunk id
            int n = chunk >> 3;
            int kcs = chunk & 7;
            int kc = kcs ^ (n & 7);                 // inverse swizzle on source
            const unsigned short* src = &Wt[(size_t)n * IN_DIM + k0 + kc * 8];
            unsigned short* dst = &Bs[(wid * 4 + p) * 512];  // wave-uniform base
            __builtin_amdgcn_global_load_lds(
                (const __attribute__((address_space(1))) u32*)(const void*)src,
                (__attribute__((address_space(3))) u32*)(void*)dst, 16, 0, 0);
        }
        __syncthreads();

#pragma unroll
        for (int kk = 0; kk < 2; kk++) {
            const int kel = kk * 32 + (lane >> 4) * 8;
            bf16x8 a[4], b[4];
#pragma unroll
            for (int mi = 0; mi < 4; mi++)
                a[mi] = *(const bf16x8*)&As[elem_off(wr0 + mi * 16 + (lane & 15), kel)];
#pragma unroll
            for (int ni = 0; ni < 4; ni++)
                b[ni] = *(const bf16x8*)&Bs[elem_off(wc0 + ni * 16 + (lane & 15), kel)];
#pragma unroll
            for (int mi = 0; mi < 4; mi++)
#pragma unroll
                for (int ni = 0; ni < 4; ni++)
                    acc[mi][ni] = __builtin_amdgcn_mfma_f32_16x16x32_bf16(
                        a[mi], b[ni], acc[mi][ni], 0, 0, 0);
        }
        __syncthreads();
    }

#pragma unroll
    for (int mi = 0; mi < 4; mi++) {
#pragma unroll
        for (int reg = 0; reg < 4; reg++) {
            int grow = brow + wr0 + mi * 16 + (lane >> 4) * 4 + reg;
            if (grow < N) {
#pragma unroll
                for (int ni = 0; ni < 4; ni++) {
                    int gcol = wc0 + ni * 16 + (lane & 15);
                    H[(size_t)grow * HD1 + gcol] = f2bf(acc[mi][ni][reg]);
                }
            }
        }
    }
}

// ---------- gather layer1: bf16 h, shfl-broadcast cols, 4 gathers in flight ----------
__global__ __launch_bounds__(256) void k_gather1(const unsigned short* __restrict__ h,
                                                 const int* __restrict__ rowptr,
                                                 const int* __restrict__ col,
                                                 const float* __restrict__ wgt,
                                                 const float* __restrict__ dinv,
                                                 const float* __restrict__ bias,
                                                 unsigned short* __restrict__ out, int N) {
    int i = (blockIdx.x * 256 + threadIdx.x) >> 6;
    int lane = threadIdx.x & 63;
    if (i >= N) return;
    const float di = dinv[i];
    u32 hv = *(const u32*)&h[(size_t)i * HD1 + 2 * lane];
    float a0 = bf_lo(hv) * (di * di);
    float a1 = bf_hi(hv) * (di * di);
    const int beg = rowptr[i], end = rowptr[i + 1];
    for (int p0 = beg; p0 < end; p0 += 64) {
        int idx = p0 + lane;
        bool ok = idx < end;
        int myj = ok ? col[idx] : i;
        float myw = ok ? wgt[idx] : 0.f;
        int cnt = min(64, end - p0);
        for (int k = 0; k < cnt; k += 4) {
            int j0 = __shfl(myj, k),     j1 = __shfl(myj, k + 1);
            int j2 = __shfl(myj, k + 2), j3 = __shfl(myj, k + 3);
            float w0 = __shfl(myw, k),     w1 = __shfl(myw, k + 1);
            float w2 = __shfl(myw, k + 2), w3 = __shfl(myw, k + 3);
            u32 v0 = *(const u32*)&h[(size_t)j0 * HD1 + 2 * lane];
            u32 v1 = *(const u32*)&h[(size_t)j1 * HD1 + 2 * lane];
            u32 v2 = *(const u32*)&h[(size_t)j2 * HD1 + 2 * lane];
            u32 v3 = *(const u32*)&h[(size_t)j3 * HD1 + 2 * lane];
            a0 = fmaf(bf_lo(v0), w0, a0); a1 = fmaf(bf_hi(v0), w0, a1);
            a0 = fmaf(bf_lo(v1), w1, a0); a1 = fmaf(bf_hi(v1), w1, a1);
            a0 = fmaf(bf_lo(v2), w2, a0); a1 = fmaf(bf_hi(v2), w2, a1);
            a0 = fmaf(bf_lo(v3), w3, a0); a1 = fmaf(bf_hi(v3), w3, a1);
        }
    }
    float2 bv = *(const float2*)&bias[2 * lane];
    float r0 = fmaxf(a0 + bv.x, 0.f);
    float r1 = fmaxf(a1 + bv.y, 0.f);
    u32 packed = (u32)f2bf(r0) | ((u32)f2bf(r1) << 16);
    *(u32*)&out[(size_t)i * HD1 + 2 * lane] = packed;
}

// ---------- GEMM2: agg1[N,128]bf16 @ Wt2[64][128]bf16 -> h2 [N,64]bf16, MFMA ----------
__global__ __launch_bounds__(256) void k_gemm2(const unsigned short* __restrict__ A,
                                               const unsigned short* __restrict__ Wt2,
                                               unsigned short* __restrict__ H, int N) {
    __shared__ unsigned short As[128 * 128];  // swizzled [row][k]
    __shared__ unsigned short Bs[64 * 128];   // swizzled [col][k]
    const int tid = threadIdx.x;
    const int lane = tid & 63;
    const int wid = tid >> 6;
    const int brow = blockIdx.x * 128;
    const int wr0 = wid * 32;

    // stage A (rows may run past N; reads stay inside padded ws buffer, stores guarded)
#pragma unroll
    for (int p = 0; p < 8; p++) {
        int chunk = (wid * 8 + p) * 64 + lane;
        int r = chunk >> 4;                 // 16 chunks per 128-elem row
        int kcs = chunk & 15;
        int kc = kcs ^ (r & 7);             // inverse swizzle on source
        const unsigned short* src = &A[(size_t)(brow + r) * HD1 + kc * 8];
        unsigned short* dst = &As[(wid * 8 + p) * 512];
        __builtin_amdgcn_global_load_lds(
            (const __attribute__((address_space(1))) u32*)(const void*)src,
            (__attribute__((address_space(3))) u32*)(void*)dst, 16, 0, 0);
    }
    // stage B
#pragma unroll
    for (int p = 0; p < 4; p++) {
        int chunk = (wid * 4 + p) * 64 + lane;
        int c = chunk >> 4;
        int kcs = chunk & 15;
        int kc = kcs ^ (c & 7);
        const unsigned short* src = &Wt2[(size_t)c * HD1 + kc * 8];
        unsigned short* dst = &Bs[(wid * 4 + p) * 512];
        __builtin_amdgcn_global_load_lds(
            (const __attribute__((address_space(1))) u32*)(const void*)src,
            (__attribute__((address_space(3))) u32*)(void*)dst, 16, 0, 0);
    }
    __syncthreads();

    f32x4 acc[2][4];
#pragma unroll
    for (int i = 0; i < 2; i++)
#pragma unroll
        for (int j = 0; j < 4; j++) acc[i][j] = (f32x4){0.f, 0.f, 0.f, 0.f};

#pragma unroll
    for (int kk = 0; kk < 4; kk++) {
        const int kel = kk * 32 + (lane >> 4) * 8;
        bf16x8 a[2], b[4];
#pragma unroll
        for (int mi = 0; mi < 2; mi++)
            a[mi] = *(const bf16x8*)&As[elem_off128(wr0 + mi * 16 + (lane & 15), kel)];
#pragma unroll
        for (int ni = 0; ni < 4; ni++)
            b[ni] = *(const bf16x8*)&Bs[elem_off128(ni * 16 + (lane & 15), kel)];
#pragma unroll
        for (int mi = 0; mi < 2; mi++)
#pragma unroll
            for (int ni = 0; ni < 4; ni++)
                acc[mi][ni] = __builtin_amdgcn_mfma_f32_16x16x32_bf16(
                    a[mi], b[ni], acc[mi][ni], 0, 0, 0);
    }

#pragma unroll
    for (int mi = 0; mi < 2; mi++) {
#pragma unroll
        for (int reg = 0; reg < 4; reg++) {
            int grow = brow + wr0 + mi * 16 + (lane >> 4) * 4 + reg;
            if (grow < N) {
#pragma unroll
                for (int ni = 0; ni < 4; ni++) {
                    int gcol = ni * 16 + (lane & 15);
                    H[(size_t)grow * HD2 + gcol] = f2bf(acc[mi][ni][reg]);
                }
            }
        }
    }
}

// ---------- gather layer2: bf16 h (64 cols), f32 out ----------
__global__ __launch_bounds__(256) void k_gather2(const unsigned short* __restrict__ h,
                                                 const int* __restrict__ rowptr,
                                                 const int* __restrict__ col,
                                                 const float* __restrict__ wgt,
                                                 const float* __restrict__ dinv,
                                                 const float* __restrict__ bias,
                                                 float* __restrict__ out, int N) {
    int i = (blockIdx.x * 256 + threadIdx.x) >> 6;
    int lane = threadIdx.x & 63;
    if (i >= N) return;
    const float di = dinv[i];
    float acc = bf_lo((u32)h[(size_t)i * HD2 + lane]) * (di * di);
    const int beg = rowptr[i], end = rowptr[i + 1];
    for (int p0 = beg; p0 < end; p0 += 64) {
        int idx = p0 + lane;
        bool ok = idx < end;
        int myj = ok ? col[idx] : i;
        float myw = ok ? wgt[idx] : 0.f;
        int cnt = min(64, end - p0);
        for (int k = 0; k < cnt; k += 4) {
            int j0 = __shfl(myj, k),     j1 = __shfl(myj, k + 1);
            int j2 = __shfl(myj, k + 2), j3 = __shfl(myj, k + 3);
            float w0 = __shfl(myw, k),     w1 = __shfl(myw, k + 1);
            float w2 = __shfl(myw, k + 2), w3 = __shfl(myw, k + 3);
            float v0 = bf_lo((u32)h[(size_t)j0 * HD2 + lane]);
            float v1 = bf_lo((u32)h[(size_t)j1 * HD2 + lane]);
            float v2 = bf_lo((u32)h[(size_t)j2 * HD2 + lane]);
            float v3 = bf_lo((u32)h[(size_t)j3 * HD2 + lane]);
            acc = fmaf(v0, w0, acc);
            acc = fmaf(v1, w1, acc);
            acc = fmaf(v2, w2, acc);
            acc = fmaf(v3, w3, acc);
        }
    }
    out[(size_t)i * HD2 + lane] = fmaxf(acc + bias[lane], 0.f);
}

extern "C" void kernel_launch(void* const* d_in, const int* in_sizes, int n_in,
                              void* d_out, int out_size, void* d_ws, size_t ws_size,
                              hipStream_t stream) {
    const float* x  = (const float*)d_in[0];
    const int*   ei = (const int*)d_in[1];
    const float* W1 = (const float*)d_in[2];
    const float* b1 = (const float*)d_in[3];
    const float* W2 = (const float*)d_in[4];
    const float* b2 = (const float*)d_in[5];
    float* out = (float*)d_out;

    const int N = in_sizes[0] / IN_DIM;     // 50000
    const int E = in_sizes[1] / 2;          // 800000
    const int* src = ei;
    const int* dst = ei + E;

    // workspace layout (256B aligned)
    char* w = (char*)d_ws;
    size_t off = 0;
    auto alloc = [&](size_t bytes) -> void* {
        void* p = w + off;
        off = (off + bytes + 255) & ~(size_t)255;
        return p;
    };
    int*   deg    = (int*)alloc((size_t)N * 4);
    int*   fill   = (int*)alloc((size_t)N * 4);
    int*   rowptr = (int*)alloc((size_t)(N + 1) * 4);
    int*   bsum   = (int*)alloc(1024 * 4);
    int*   col    = (int*)alloc((size_t)E * 4);
    float* wgt    = (float*)alloc((size_t)E * 4);
    float* dinv   = (float*)alloc((size_t)N * 4);
    unsigned short* Wt  = (unsigned short*)alloc((size_t)IN_DIM * HD1 * 2);
    unsigned short* Wt2 = (unsigned short*)alloc((size_t)HD2 * HD1 * 2);
    unsigned short* h1  = (unsigned short*)alloc((size_t)N * HD1 * 2);          // bf16
    unsigned short* agg1= (unsigned short*)alloc((size_t)(N + 128) * HD1 * 2);  // bf16, padded
    unsigned short* h2  = h1;  // h1 dead after gather1; N*64*2 <= N*128*2

    hipMemsetAsync(deg, 0, (size_t)N * 4, stream);
    hipMemsetAsync(fill, 0, (size_t)N * 4, stream);

    const int nb = (N + 255) / 256;
    const int eb = (E + 255) / 256;

    k_deg<<<eb, 256, 0, stream>>>(dst, E, deg);
    k_dinv<<<nb, 256, 0, stream>>>(deg, dinv, N);
    k_blocksum<<<nb, 256, 0, stream>>>(deg, N, bsum);
    k_scan_bsum<<<1, 1024, 0, stream>>>(bsum, nb);
    k_scan_final<<<nb, 256, 0, stream>>>(deg, N, bsum, rowptr);
    k_fill<<<eb, 256, 0, stream>>>(src, dst, E, rowptr, dinv, fill, col, wgt);
    k_wt<<<IN_DIM * HD1 / 256, 256, 0, stream>>>(W1, Wt);
    k_wt2<<<HD2 * HD1 / 256, 256, 0, stream>>>(W2, Wt2);

    k_gemm1<<<(N + 127) / 128, 256, 0, stream>>>(x, Wt, h1, N);
    k_gather1<<<(N * 64 + 255) / 256, 256, 0, stream>>>(h1, rowptr, col, wgt, dinv, b1, agg1, N);
    k_gemm2<<<(N + 127) / 128, 256, 0, stream>>>(agg1, Wt2, h2, N);
    k_gather2<<<(N * 64 + 255) / 256, 256, 0, stream>>>(h2, rowptr, col, wgt, dinv, b2, out, N);
}

// Round 4
// 186.275 us; speedup vs baseline: 2.2986x; 1.0335x over previous
//
#include <hip/hip_runtime.h>

// 2-layer GCN: h = relu(Anorm @ (x@W1) + b1); out = relu(Anorm @ (h@W2) + b2)
// Round 3: gathers get edge-pairing (half-wave per edge) + 2-deep software
// pipeline (8 gathers in flight); gemm1 issues B gload_lds before A staging.

constexpr int IN_DIM = 512;
constexpr int HD1 = 128;
constexpr int HD2 = 64;

typedef __attribute__((ext_vector_type(8))) short bf16x8;
typedef __attribute__((ext_vector_type(8))) unsigned short u16x8;
typedef __attribute__((ext_vector_type(4))) float f32x4;
typedef unsigned int u32;

__device__ inline unsigned short f2bf(float f) {
    u32 u = __builtin_bit_cast(u32, f);
    return (unsigned short)((u + 0x7fffu + ((u >> 16) & 1u)) >> 16);
}
__device__ inline float bf_lo(u32 v) { return __builtin_bit_cast(float, v << 16); }
__device__ inline float bf_hi(u32 v) { return __builtin_bit_cast(float, v & 0xffff0000u); }

// swizzled LDS element offset, [row][64] bf16 tiles
__device__ inline int elem_off(int row, int k) {
    return (row << 6) + (k ^ ((row & 7) << 3));
}
// swizzled LDS element offset, [row][128] bf16 tiles
__device__ inline int elem_off128(int row, int k) {
    return (row << 7) + (k ^ ((row & 7) << 3));
}

// ---------- degree / norm ----------
__global__ __launch_bounds__(256) void k_deg(const int* __restrict__ dst, int E,
                                             int* __restrict__ deg) {
    int e = blockIdx.x * 256 + threadIdx.x;
    if (e < E) atomicAdd(&deg[dst[e]], 1);
}

__global__ __launch_bounds__(256) void k_dinv(const int* __restrict__ deg,
                                              float* __restrict__ dinv, int N) {
    int i = blockIdx.x * 256 + threadIdx.x;
    if (i < N) dinv[i] = rsqrtf((float)(deg[i] + 1));  // +1 = self loop
}

// ---------- prefix scan (3-phase) for CSR rowptr ----------
__global__ __launch_bounds__(256) void k_blocksum(const int* __restrict__ deg, int N,
                                                  int* __restrict__ bsum) {
    __shared__ int s[256];
    int t = threadIdx.x;
    int i = blockIdx.x * 256 + t;
    s[t] = (i < N) ? deg[i] : 0;
    __syncthreads();
    for (int st = 128; st > 0; st >>= 1) {
        if (t < st) s[t] += s[t + st];
        __syncthreads();
    }
    if (t == 0) bsum[blockIdx.x] = s[0];
}

__global__ __launch_bounds__(1024) void k_scan_bsum(int* __restrict__ bsum, int nb) {
    __shared__ int s[1024];
    int t = threadIdx.x;
    s[t] = (t < nb) ? bsum[t] : 0;
    __syncthreads();
    for (int off = 1; off < 1024; off <<= 1) {
        int v = (t >= off) ? s[t - off] : 0;
        __syncthreads();
        s[t] += v;
        __syncthreads();
    }
    if (t < nb) bsum[t] = (t == 0) ? 0 : s[t - 1];  // exclusive
}

__global__ __launch_bounds__(256) void k_scan_final(const int* __restrict__ deg, int N,
                                                    const int* __restrict__ bsum,
                                                    int* __restrict__ rowptr) {
    __shared__ int s[256];
    int t = threadIdx.x;
    int i = blockIdx.x * 256 + t;
    int v = (i < N) ? deg[i] : 0;
    s[t] = v;
    __syncthreads();
    for (int off = 1; off < 256; off <<= 1) {
        int u = (t >= off) ? s[t - off] : 0;
        __syncthreads();
        s[t] += u;
        __syncthreads();
    }
    int incl = s[t] + bsum[blockIdx.x];
    if (i < N) rowptr[i] = incl - v;
    if (i == N - 1) rowptr[N] = incl;
}

__global__ __launch_bounds__(256) void k_fill(const int* __restrict__ src,
                                              const int* __restrict__ dst, int E,
                                              const int* __restrict__ rowptr,
                                              const float* __restrict__ dinv,
                                              int* __restrict__ fill,
                                              int* __restrict__ col,
                                              float* __restrict__ wgt) {
    int e = blockIdx.x * 256 + threadIdx.x;
    if (e < E) {
        int s = src[e], d = dst[e];
        int pos = rowptr[d] + atomicAdd(&fill[d], 1);
        col[pos] = s;
        wgt[pos] = dinv[s] * dinv[d];
    }
}

// ---------- weight transposes -> bf16 ----------
__global__ __launch_bounds__(256) void k_wt(const float* __restrict__ W1,
                                            unsigned short* __restrict__ Wt) {
    int id = blockIdx.x * 256 + threadIdx.x;   // 65536
    int n = id >> 9, k = id & 511;
    Wt[id] = f2bf(W1[k * HD1 + n]);
}

__global__ __launch_bounds__(256) void k_wt2(const float* __restrict__ W2,
                                             unsigned short* __restrict__ Wt2) {
    int id = blockIdx.x * 256 + threadIdx.x;   // 8192
    int n = id >> 7, k = id & 127;
    Wt2[id] = f2bf(W2[k * HD2 + n]);
}

// ---------- GEMM1: [N,512]f32 @ Wt[128][512]bf16 -> h1 [N,128]bf16, MFMA ----------
__global__ __launch_bounds__(256) void k_gemm1(const float* __restrict__ X,
                                               const unsigned short* __restrict__ Wt,
                                               unsigned short* __restrict__ H, int N) {
    __shared__ unsigned short As[128 * 64];  // x tile, swizzled [row][k]
    __shared__ unsigned short Bs[128 * 64];  // W tile, swizzled [col][k]

    const int tid = threadIdx.x;
    const int lane = tid & 63;
    const int wid = tid >> 6;
    const int brow = blockIdx.x * 128;
    const int wr0 = (wid >> 1) * 64;
    const int wc0 = (wid & 1) * 64;
    const bool full = (brow + 128 <= N);

    f32x4 acc[4][4];
#pragma unroll
    for (int i = 0; i < 4; i++)
#pragma unroll
        for (int j = 0; j < 4; j++) acc[i][j] = (f32x4){0.f, 0.f, 0.f, 0.f};

    for (int kt = 0; kt < IN_DIM / 64; kt++) {
        const int k0 = kt * 64;
        // ---- issue B first: global_load_lds streams while A-staging runs ----
#pragma unroll
        for (int p = 0; p < 4; p++) {
            int chunk = (wid * 4 + p) * 64 + lane;  // 16B chunk id
            int n = chunk >> 3;
            int kcs = chunk & 7;
            int kc = kcs ^ (n & 7);                 // inverse swizzle on source
            const unsigned short* src = &Wt[(size_t)n * IN_DIM + k0 + kc * 8];
            unsigned short* dst = &Bs[(wid * 4 + p) * 512];  // wave-uniform base
            __builtin_amdgcn_global_load_lds(
                (const __attribute__((address_space(1))) u32*)(const void*)src,
                (__attribute__((address_space(3))) u32*)(void*)dst, 16, 0, 0);
        }
        // ---- stage A: 128 rows x 64 k, f32 -> bf16, reg-staged ----
#pragma unroll
        for (int p = 0; p < 4; p++) {
            int chunk = tid + p * 256;     // 1024 chunks of 8 elems
            int r = chunk >> 3;
            int kc = chunk & 7;
            const float* xp = &X[(size_t)(brow + r) * IN_DIM + k0 + kc * 8];
            float4 v0, v1;
            if (full || (brow + r) < N) {
                v0 = *(const float4*)xp;
                v1 = *(const float4*)(xp + 4);
            } else {
                v0 = make_float4(0.f, 0.f, 0.f, 0.f); v1 = v0;
            }
            u16x8 w;
            w[0] = f2bf(v0.x); w[1] = f2bf(v0.y); w[2] = f2bf(v0.z); w[3] = f2bf(v0.w);
            w[4] = f2bf(v1.x); w[5] = f2bf(v1.y); w[6] = f2bf(v1.z); w[7] = f2bf(v1.w);
            *(u16x8*)&As[elem_off(r, kc * 8)] = w;
        }
        __syncthreads();

#pragma unroll
        for (int kk = 0; kk < 2; kk++) {
            const int kel = kk * 32 + (lane >> 4) * 8;
            bf16x8 a[4], b[4];
#pragma unroll
            for (int mi = 0; mi < 4; mi++)
                a[mi] = *(const bf16x8*)&As[elem_off(wr0 + mi * 16 + (lane & 15), kel)];
#pragma unroll
            for (int ni = 0; ni < 4; ni++)
                b[ni] = *(const bf16x8*)&Bs[elem_off(wc0 + ni * 16 + (lane & 15), kel)];
#pragma unroll
            for (int mi = 0; mi < 4; mi++)
#pragma unroll
                for (int ni = 0; ni < 4; ni++)
                    acc[mi][ni] = __builtin_amdgcn_mfma_f32_16x16x32_bf16(
                        a[mi], b[ni], acc[mi][ni], 0, 0, 0);
        }
        __syncthreads();
    }

#pragma unroll
    for (int mi = 0; mi < 4; mi++) {
#pragma unroll
        for (int reg = 0; reg < 4; reg++) {
            int grow = brow + wr0 + mi * 16 + (lane >> 4) * 4 + reg;
            if (grow < N) {
#pragma unroll
                for (int ni = 0; ni < 4; ni++) {
                    int gcol = wc0 + ni * 16 + (lane & 15);
                    H[(size_t)grow * HD1 + gcol] = f2bf(acc[mi][ni][reg]);
                }
            }
        }
    }
}

// ---------- gather layer1: paired half-wave edges, 2-deep pipelined gathers ----------
// lanes 0-31 process even edges, 32-63 odd edges; each lane owns 4 cols (8B load).
__global__ __launch_bounds__(256) void k_gather1(const unsigned short* __restrict__ h,
                                                 const int* __restrict__ rowptr,
                                                 const int* __restrict__ col,
                                                 const float* __restrict__ wgt,
                                                 const float* __restrict__ dinv,
                                                 const float* __restrict__ bias,
                                                 unsigned short* __restrict__ out, int N) {
    const int i = (blockIdx.x * 256 + threadIdx.x) >> 6;
    const int lane = threadIdx.x & 63;
    if (i >= N) return;
    const int half = lane >> 5;
    const int c4 = (lane & 31) * 4;           // my 4 columns
    const float di = dinv[i];
    const unsigned short* hc = h + c4;

    float a0 = 0.f, a1 = 0.f, a2 = 0.f, a3 = 0.f;
    if (half == 0) {  // self-loop term counted once
        uint2 sv = *(const uint2*)&hc[(size_t)i * HD1];
        float s = di * di;
        a0 = bf_lo(sv.x) * s; a1 = bf_hi(sv.x) * s;
        a2 = bf_lo(sv.y) * s; a3 = bf_hi(sv.y) * s;
    }
    const int beg = rowptr[i], end = rowptr[i + 1];
    for (int p0 = beg; p0 < end; p0 += 64) {
        int idx = p0 + lane;
        bool okl = idx < end;
        int myj = okl ? col[idx] : i;
        float myw = okl ? wgt[idx] : 0.f;
        const int cnt8 = (min(64, end - p0) + 7) & ~7;
        uint2 v[4]; float wv[4];
#pragma unroll
        for (int q = 0; q < 4; q++) {          // prologue: edges 0..7
            int e = 2 * q + half;
            int j = __shfl(myj, e);
            wv[q] = __shfl(myw, e);
            v[q] = *(const uint2*)&hc[(size_t)j * HD1];
        }
        for (int k = 8; k < cnt8; k += 8) {
            uint2 nv[4]; float nw[4];
#pragma unroll
            for (int q = 0; q < 4; q++) {      // issue next 8 gathers first
                int e = k + 2 * q + half;
                int j = __shfl(myj, e);
                nw[q] = __shfl(myw, e);
                nv[q] = *(const uint2*)&hc[(size_t)j * HD1];
            }
#pragma unroll
            for (int q = 0; q < 4; q++) {      // consume previous 8
                a0 = fmaf(bf_lo(v[q].x), wv[q], a0);
                a1 = fmaf(bf_hi(v[q].x), wv[q], a1);
                a2 = fmaf(bf_lo(v[q].y), wv[q], a2);
                a3 = fmaf(bf_hi(v[q].y), wv[q], a3);
            }
#pragma unroll
            for (int q = 0; q < 4; q++) { v[q] = nv[q]; wv[q] = nw[q]; }
        }
#pragma unroll
        for (int q = 0; q < 4; q++) {
            a0 = fmaf(bf_lo(v[q].x), wv[q], a0);
            a1 = fmaf(bf_hi(v[q].x), wv[q], a1);
            a2 = fmaf(bf_lo(v[q].y), wv[q], a2);
            a3 = fmaf(bf_hi(v[q].y), wv[q], a3);
        }
    }
    // combine even/odd halves
    a0 += __shfl_xor(a0, 32);
    a1 += __shfl_xor(a1, 32);
    a2 += __shfl_xor(a2, 32);
    a3 += __shfl_xor(a3, 32);
    if (half == 0) {
        float4 bv = *(const float4*)&bias[c4];
        u32 w0 = (u32)f2bf(fmaxf(a0 + bv.x, 0.f)) | ((u32)f2bf(fmaxf(a1 + bv.y, 0.f)) << 16);
        u32 w1 = (u32)f2bf(fmaxf(a2 + bv.z, 0.f)) | ((u32)f2bf(fmaxf(a3 + bv.w, 0.f)) << 16);
        *(uint2*)&out[(size_t)i * HD1 + c4] = make_uint2(w0, w1);
    }
}

// ---------- GEMM2: agg1[N,128]bf16 @ Wt2[64][128]bf16 -> h2 [N,64]bf16, MFMA ----------
__global__ __launch_bounds__(256) void k_gemm2(const unsigned short* __restrict__ A,
                                               const unsigned short* __restrict__ Wt2,
                                               unsigned short* __restrict__ H, int N) {
    __shared__ unsigned short As[128 * 128];  // swizzled [row][k]
    __shared__ unsigned short Bs[64 * 128];   // swizzled [col][k]
    const int tid = threadIdx.x;
    const int lane = tid & 63;
    const int wid = tid >> 6;
    const int brow = blockIdx.x * 128;
    const int wr0 = wid * 32;

#pragma unroll
    for (int p = 0; p < 8; p++) {
        int chunk = (wid * 8 + p) * 64 + lane;
        int r = chunk >> 4;                 // 16 chunks per 128-elem row
        int kcs = chunk & 15;
        int kc = kcs ^ (r & 7);             // inverse swizzle on source
        const unsigned short* src = &A[(size_t)(brow + r) * HD1 + kc * 8];
        unsigned short* dst = &As[(wid * 8 + p) * 512];
        __builtin_amdgcn_global_load_lds(
            (const __attribute__((address_space(1))) u32*)(const void*)src,
            (__attribute__((address_space(3))) u32*)(void*)dst, 16, 0, 0);
    }
#pragma unroll
    for (int p = 0; p < 4; p++) {
        int chunk = (wid * 4 + p) * 64 + lane;
        int c = chunk >> 4;
        int kcs = chunk & 15;
        int kc = kcs ^ (c & 7);
        const unsigned short* src = &Wt2[(size_t)c * HD1 + kc * 8];
        unsigned short* dst = &Bs[(wid * 4 + p) * 512];
        __builtin_amdgcn_global_load_lds(
            (const __attribute__((address_space(1))) u32*)(const void*)src,
            (__attribute__((address_space(3))) u32*)(void*)dst, 16, 0, 0);
    }
    __syncthreads();

    f32x4 acc[2][4];
#pragma unroll
    for (int i = 0; i < 2; i++)
#pragma unroll
        for (int j = 0; j < 4; j++) acc[i][j] = (f32x4){0.f, 0.f, 0.f, 0.f};

#pragma unroll
    for (int kk = 0; kk < 4; kk++) {
        const int kel = kk * 32 + (lane >> 4) * 8;
        bf16x8 a[2], b[4];
#pragma unroll
        for (int mi = 0; mi < 2; mi++)
            a[mi] = *(const bf16x8*)&As[elem_off128(wr0 + mi * 16 + (lane & 15), kel)];
#pragma unroll
        for (int ni = 0; ni < 4; ni++)
            b[ni] = *(const bf16x8*)&Bs[elem_off128(ni * 16 + (lane & 15), kel)];
#pragma unroll
        for (int mi = 0; mi < 2; mi++)
#pragma unroll
            for (int ni = 0; ni < 4; ni++)
                acc[mi][ni] = __builtin_amdgcn_mfma_f32_16x16x32_bf16(
                    a[mi], b[ni], acc[mi][ni], 0, 0, 0);
    }

#pragma unroll
    for (int mi = 0; mi < 2; mi++) {
#pragma unroll
        for (int reg = 0; reg < 4; reg++) {
            int grow = brow + wr0 + mi * 16 + (lane >> 4) * 4 + reg;
            if (grow < N) {
#pragma unroll
                for (int ni = 0; ni < 4; ni++) {
                    int gcol = ni * 16 + (lane & 15);
                    H[(size_t)grow * HD2 + gcol] = f2bf(acc[mi][ni][reg]);
                }
            }
        }
    }
}

// ---------- gather layer2: paired half-wave edges, 2-deep pipeline, f32 out ----------
__global__ __launch_bounds__(256) void k_gather2(const unsigned short* __restrict__ h,
                                                 const int* __restrict__ rowptr,
                                                 const int* __restrict__ col,
                                                 const float* __restrict__ wgt,
                                                 const float* __restrict__ dinv,
                                                 const float* __restrict__ bias,
                                                 float* __restrict__ out, int N) {
    const int i = (blockIdx.x * 256 + threadIdx.x) >> 6;
    const int lane = threadIdx.x & 63;
    if (i >= N) return;
    const int half = lane >> 5;
    const int c2 = (lane & 31) * 2;           // my 2 columns
    const float di = dinv[i];
    const unsigned short* hc = h + c2;

    float a0 = 0.f, a1 = 0.f;
    if (half == 0) {
        u32 sv = *(const u32*)&hc[(size_t)i * HD2];
        float s = di * di;
        a0 = bf_lo(sv) * s; a1 = bf_hi(sv) * s;
    }
    const int beg = rowptr[i], end = rowptr[i + 1];
    for (int p0 = beg; p0 < end; p0 += 64) {
        int idx = p0 + lane;
        bool okl = idx < end;
        int myj = okl ? col[idx] : i;
        float myw = okl ? wgt[idx] : 0.f;
        const int cnt8 = (min(64, end - p0) + 7) & ~7;
        u32 v[4]; float wv[4];
#pragma unroll
        for (int q = 0; q < 4; q++) {
            int e = 2 * q + half;
            int j = __shfl(myj, e);
            wv[q] = __shfl(myw, e);
            v[q] = *(const u32*)&hc[(size_t)j * HD2];
        }
        for (int k = 8; k < cnt8; k += 8) {
            u32 nv[4]; float nw[4];
#pragma unroll
            for (int q = 0; q < 4; q++) {
                int e = k + 2 * q + half;
                int j = __shfl(myj, e);
                nw[q] = __shfl(myw, e);
                nv[q] = *(const u32*)&hc[(size_t)j * HD2];
            }
#pragma unroll
            for (int q = 0; q < 4; q++) {
                a0 = fmaf(bf_lo(v[q]), wv[q], a0);
                a1 = fmaf(bf_hi(v[q]), wv[q], a1);
            }
#pragma unroll
            for (int q = 0; q < 4; q++) { v[q] = nv[q]; wv[q] = nw[q]; }
        }
#pragma unroll
        for (int q = 0; q < 4; q++) {
            a0 = fmaf(bf_lo(v[q]), wv[q], a0);
            a1 = fmaf(bf_hi(v[q]), wv[q], a1);
        }
    }
    a0 += __shfl_xor(a0, 32);
    a1 += __shfl_xor(a1, 32);
    if (half == 0) {
        float2 bv = *(const float2*)&bias[c2];
        float2 r = make_float2(fmaxf(a0 + bv.x, 0.f), fmaxf(a1 + bv.y, 0.f));
        *(float2*)&out[(size_t)i * HD2 + c2] = r;
    }
}

extern "C" void kernel_launch(void* const* d_in, const int* in_sizes, int n_in,
                              void* d_out, int out_size, void* d_ws, size_t ws_size,
                              hipStream_t stream) {
    const float* x  = (const float*)d_in[0];
    const int*   ei = (const int*)d_in[1];
    const float* W1 = (const float*)d_in[2];
    const float* b1 = (const float*)d_in[3];
    const float* W2 = (const float*)d_in[4];
    const float* b2 = (const float*)d_in[5];
    float* out = (float*)d_out;

    const int N = in_sizes[0] / IN_DIM;     // 50000
    const int E = in_sizes[1] / 2;          // 800000
    const int* src = ei;
    const int* dst = ei + E;

    // workspace layout (256B aligned)
    char* w = (char*)d_ws;
    size_t off = 0;
    auto alloc = [&](size_t bytes) -> void* {
        void* p = w + off;
        off = (off + bytes + 255) & ~(size_t)255;
        return p;
    };
    int*   deg    = (int*)alloc((size_t)N * 4);
    int*   fill   = (int*)alloc((size_t)N * 4);
    int*   rowptr = (int*)alloc((size_t)(N + 1) * 4);
    int*   bsum   = (int*)alloc(1024 * 4);
    int*   col    = (int*)alloc((size_t)E * 4);
    float* wgt    = (float*)alloc((size_t)E * 4);
    float* dinv   = (float*)alloc((size_t)N * 4);
    unsigned short* Wt  = (unsigned short*)alloc((size_t)IN_DIM * HD1 * 2);
    unsigned short* Wt2 = (unsigned short*)alloc((size_t)HD2 * HD1 * 2);
    unsigned short* h1  = (unsigned short*)alloc((size_t)N * HD1 * 2);          // bf16
    unsigned short* agg1= (unsigned short*)alloc((size_t)(N + 128) * HD1 * 2);  // bf16, padded
    unsigned short* h2  = h1;  // h1 dead after gather1; N*64*2 <= N*128*2

    hipMemsetAsync(deg, 0, (size_t)N * 4, stream);
    hipMemsetAsync(fill, 0, (size_t)N * 4, stream);

    const int nb = (N + 255) / 256;
    const int eb = (E + 255) / 256;

    k_deg<<<eb, 256, 0, stream>>>(dst, E, deg);
    k_dinv<<<nb, 256, 0, stream>>>(deg, dinv, N);
    k_blocksum<<<nb, 256, 0, stream>>>(deg, N, bsum);
    k_scan_bsum<<<1, 1024, 0, stream>>>(bsum, nb);
    k_scan_final<<<nb, 256, 0, stream>>>(deg, N, bsum, rowptr);
    k_fill<<<eb, 256, 0, stream>>>(src, dst, E, rowptr, dinv, fill, col, wgt);
    k_wt<<<IN_DIM * HD1 / 256, 256, 0, stream>>>(W1, Wt);
    k_wt2<<<HD2 * HD1 / 256, 256, 0, stream>>>(W2, Wt2);

    k_gemm1<<<(N + 127) / 128, 256, 0, stream>>>(x, Wt, h1, N);
    k_gather1<<<(N * 64 + 255) / 256, 256, 0, stream>>>(h1, rowptr, col, wgt, dinv, b1, agg1, N);
    k_gemm2<<<(N + 127) / 128, 256, 0, stream>>>(agg1, Wt2, h2, N);
    k_gather2<<<(N * 64 + 255) / 256, 256, 0, stream>>>(h2, rowptr, col, wgt, dinv, b2, out, N);
}

// Round 5
// 179.408 us; speedup vs baseline: 2.3866x; 1.0383x over previous
//
#include <hip/hip_runtime.h>

// 2-layer GCN: h = relu(Anorm @ (x@W1) + b1); out = relu(Anorm @ (h@W2) + b2)
// Round 5: fuse preprocessing kernels (16 -> 11 graph nodes) to test the
// launch-gap theory. Compute kernels byte-identical to round 4.

constexpr int IN_DIM = 512;
constexpr int HD1 = 128;
constexpr int HD2 = 64;

typedef __attribute__((ext_vector_type(8))) short bf16x8;
typedef __attribute__((ext_vector_type(8))) unsigned short u16x8;
typedef __attribute__((ext_vector_type(4))) float f32x4;
typedef unsigned int u32;

__device__ inline unsigned short f2bf(float f) {
    u32 u = __builtin_bit_cast(u32, f);
    return (unsigned short)((u + 0x7fffu + ((u >> 16) & 1u)) >> 16);
}
__device__ inline float bf_lo(u32 v) { return __builtin_bit_cast(float, v << 16); }
__device__ inline float bf_hi(u32 v) { return __builtin_bit_cast(float, v & 0xffff0000u); }

// swizzled LDS element offset, [row][64] bf16 tiles
__device__ inline int elem_off(int row, int k) {
    return (row << 6) + (k ^ ((row & 7) << 3));
}
// swizzled LDS element offset, [row][128] bf16 tiles
__device__ inline int elem_off128(int row, int k) {
    return (row << 7) + (k ^ ((row & 7) << 3));
}

// ---------- fused prep: deg atomics + W1^T bf16 + W2^T bf16 ----------
__global__ __launch_bounds__(256) void k_prep(const int* __restrict__ dst, int E,
                                              int* __restrict__ deg,
                                              const float* __restrict__ W1,
                                              unsigned short* __restrict__ Wt,
                                              const float* __restrict__ W2,
                                              unsigned short* __restrict__ Wt2) {
    int id = blockIdx.x * 256 + threadIdx.x;
    if (id < E) atomicAdd(&deg[dst[id]], 1);
    if (id < IN_DIM * HD1) {                    // 65536: W1^T
        int n = id >> 9, k = id & 511;
        Wt[id] = f2bf(W1[k * HD1 + n]);
    }
    if (id < HD1 * HD2) {                       // 8192: W2^T
        int n = id >> 7, k = id & 127;
        Wt2[id] = f2bf(W2[k * HD2 + n]);
    }
}

// ---------- dinv + per-block degree sums (fused) ----------
__global__ __launch_bounds__(256) void k_dinv_bsum(const int* __restrict__ deg, int N,
                                                   float* __restrict__ dinv,
                                                   int* __restrict__ bsum) {
    __shared__ int s[256];
    int t = threadIdx.x;
    int i = blockIdx.x * 256 + t;
    int d = (i < N) ? deg[i] : 0;
    if (i < N) dinv[i] = rsqrtf((float)(d + 1));  // +1 = self loop
    s[t] = d;
    __syncthreads();
    for (int st = 128; st > 0; st >>= 1) {
        if (t < st) s[t] += s[t + st];
        __syncthreads();
    }
    if (t == 0) bsum[blockIdx.x] = s[0];
}

__global__ __launch_bounds__(1024) void k_scan_bsum(int* __restrict__ bsum, int nb) {
    __shared__ int s[1024];
    int t = threadIdx.x;
    s[t] = (t < nb) ? bsum[t] : 0;
    __syncthreads();
    for (int off = 1; off < 1024; off <<= 1) {
        int v = (t >= off) ? s[t - off] : 0;
        __syncthreads();
        s[t] += v;
        __syncthreads();
    }
    if (t < nb) bsum[t] = (t == 0) ? 0 : s[t - 1];  // exclusive
}

__global__ __launch_bounds__(256) void k_scan_final(const int* __restrict__ deg, int N,
                                                    const int* __restrict__ bsum,
                                                    int* __restrict__ rowptr) {
    __shared__ int s[256];
    int t = threadIdx.x;
    int i = blockIdx.x * 256 + t;
    int v = (i < N) ? deg[i] : 0;
    s[t] = v;
    __syncthreads();
    for (int off = 1; off < 256; off <<= 1) {
        int u = (t >= off) ? s[t - off] : 0;
        __syncthreads();
        s[t] += u;
        __syncthreads();
    }
    int incl = s[t] + bsum[blockIdx.x];
    if (i < N) rowptr[i] = incl - v;
    if (i == N - 1) rowptr[N] = incl;
}

__global__ __launch_bounds__(256) void k_fill(const int* __restrict__ src,
                                              const int* __restrict__ dst, int E,
                                              const int* __restrict__ rowptr,
                                              const float* __restrict__ dinv,
                                              int* __restrict__ fill,
                                              int* __restrict__ col,
                                              float* __restrict__ wgt) {
    int e = blockIdx.x * 256 + threadIdx.x;
    if (e < E) {
        int s = src[e], d = dst[e];
        int pos = rowptr[d] + atomicAdd(&fill[d], 1);
        col[pos] = s;
        wgt[pos] = dinv[s] * dinv[d];
    }
}

// ---------- GEMM1: [N,512]f32 @ Wt[128][512]bf16 -> h1 [N,128]bf16, MFMA ----------
__global__ __launch_bounds__(256) void k_gemm1(const float* __restrict__ X,
                                               const unsigned short* __restrict__ Wt,
                                               unsigned short* __restrict__ H, int N) {
    __shared__ unsigned short As[128 * 64];  // x tile, swizzled [row][k]
    __shared__ unsigned short Bs[128 * 64];  // W tile, swizzled [col][k]

    const int tid = threadIdx.x;
    const int lane = tid & 63;
    const int wid = tid >> 6;
    const int brow = blockIdx.x * 128;
    const int wr0 = (wid >> 1) * 64;
    const int wc0 = (wid & 1) * 64;
    const bool full = (brow + 128 <= N);

    f32x4 acc[4][4];
#pragma unroll
    for (int i = 0; i < 4; i++)
#pragma unroll
        for (int j = 0; j < 4; j++) acc[i][j] = (f32x4){0.f, 0.f, 0.f, 0.f};

    for (int kt = 0; kt < IN_DIM / 64; kt++) {
        const int k0 = kt * 64;
        // ---- issue B first: global_load_lds streams while A-staging runs ----
#pragma unroll
        for (int p = 0; p < 4; p++) {
            int chunk = (wid * 4 + p) * 64 + lane;  // 16B chunk id
            int n = chunk >> 3;
            int kcs = chunk & 7;
            int kc = kcs ^ (n & 7);                 // inverse swizzle on source
            const unsigned short* src = &Wt[(size_t)n * IN_DIM + k0 + kc * 8];
            unsigned short* dst = &Bs[(wid * 4 + p) * 512];  // wave-uniform base
            __builtin_amdgcn_global_load_lds(
                (const __attribute__((address_space(1))) u32*)(const void*)src,
                (__attribute__((address_space(3))) u32*)(void*)dst, 16, 0, 0);
        }
        // ---- stage A: 128 rows x 64 k, f32 -> bf16, reg-staged ----
#pragma unroll
        for (int p = 0; p < 4; p++) {
            int chunk = tid + p * 256;     // 1024 chunks of 8 elems
            int r = chunk >> 3;
            int kc = chunk & 7;
            const float* xp = &X[(size_t)(brow + r) * IN_DIM + k0 + kc * 8];
            float4 v0, v1;
            if (full || (brow + r) < N) {
                v0 = *(const float4*)xp;
                v1 = *(const float4*)(xp + 4);
            } else {
                v0 = make_float4(0.f, 0.f, 0.f, 0.f); v1 = v0;
            }
            u16x8 w;
            w[0] = f2bf(v0.x); w[1] = f2bf(v0.y); w[2] = f2bf(v0.z); w[3] = f2bf(v0.w);
            w[4] = f2bf(v1.x); w[5] = f2bf(v1.y); w[6] = f2bf(v1.z); w[7] = f2bf(v1.w);
            *(u16x8*)&As[elem_off(r, kc * 8)] = w;
        }
        __syncthreads();

#pragma unroll
        for (int kk = 0; kk < 2; kk++) {
            const int kel = kk * 32 + (lane >> 4) * 8;
            bf16x8 a[4], b[4];
#pragma unroll
            for (int mi = 0; mi < 4; mi++)
                a[mi] = *(const bf16x8*)&As[elem_off(wr0 + mi * 16 + (lane & 15), kel)];
#pragma unroll
            for (int ni = 0; ni < 4; ni++)
                b[ni] = *(const bf16x8*)&Bs[elem_off(wc0 + ni * 16 + (lane & 15), kel)];
#pragma unroll
            for (int mi = 0; mi < 4; mi++)
#pragma unroll
                for (int ni = 0; ni < 4; ni++)
                    acc[mi][ni] = __builtin_amdgcn_mfma_f32_16x16x32_bf16(
                        a[mi], b[ni], acc[mi][ni], 0, 0, 0);
        }
        __syncthreads();
    }

#pragma unroll
    for (int mi = 0; mi < 4; mi++) {
#pragma unroll
        for (int reg = 0; reg < 4; reg++) {
            int grow = brow + wr0 + mi * 16 + (lane >> 4) * 4 + reg;
            if (grow < N) {
#pragma unroll
                for (int ni = 0; ni < 4; ni++) {
                    int gcol = wc0 + ni * 16 + (lane & 15);
                    H[(size_t)grow * HD1 + gcol] = f2bf(acc[mi][ni][reg]);
                }
            }
        }
    }
}

// ---------- gather layer1: paired half-wave edges, 2-deep pipelined gathers ----------
__global__ __launch_bounds__(256) void k_gather1(const unsigned short* __restrict__ h,
                                                 const int* __restrict__ rowptr,
                                                 const int* __restrict__ col,
                                                 const float* __restrict__ wgt,
                                                 const float* __restrict__ dinv,
                                                 const float* __restrict__ bias,
                                                 unsigned short* __restrict__ out, int N) {
    const int i = (blockIdx.x * 256 + threadIdx.x) >> 6;
    const int lane = threadIdx.x & 63;
    if (i >= N) return;
    const int half = lane >> 5;
    const int c4 = (lane & 31) * 4;           // my 4 columns
    const float di = dinv[i];
    const unsigned short* hc = h + c4;

    float a0 = 0.f, a1 = 0.f, a2 = 0.f, a3 = 0.f;
    if (half == 0) {  // self-loop term counted once
        uint2 sv = *(const uint2*)&hc[(size_t)i * HD1];
        float s = di * di;
        a0 = bf_lo(sv.x) * s; a1 = bf_hi(sv.x) * s;
        a2 = bf_lo(sv.y) * s; a3 = bf_hi(sv.y) * s;
    }
    const int beg = rowptr[i], end = rowptr[i + 1];
    for (int p0 = beg; p0 < end; p0 += 64) {
        int idx = p0 + lane;
        bool okl = idx < end;
        int myj = okl ? col[idx] : i;
        float myw = okl ? wgt[idx] : 0.f;
        const int cnt8 = (min(64, end - p0) + 7) & ~7;
        uint2 v[4]; float wv[4];
#pragma unroll
        for (int q = 0; q < 4; q++) {          // prologue: edges 0..7
            int e = 2 * q + half;
            int j = __shfl(myj, e);
            wv[q] = __shfl(myw, e);
            v[q] = *(const uint2*)&hc[(size_t)j * HD1];
        }
        for (int k = 8; k < cnt8; k += 8) {
            uint2 nv[4]; float nw[4];
#pragma unroll
            for (int q = 0; q < 4; q++) {      // issue next 8 gathers first
                int e = k + 2 * q + half;
                int j = __shfl(myj, e);
                nw[q] = __shfl(myw, e);
                nv[q] = *(const uint2*)&hc[(size_t)j * HD1];
            }
#pragma unroll
            for (int q = 0; q < 4; q++) {      // consume previous 8
                a0 = fmaf(bf_lo(v[q].x), wv[q], a0);
                a1 = fmaf(bf_hi(v[q].x), wv[q], a1);
                a2 = fmaf(bf_lo(v[q].y), wv[q], a2);
                a3 = fmaf(bf_hi(v[q].y), wv[q], a3);
            }
#pragma unroll
            for (int q = 0; q < 4; q++) { v[q] = nv[q]; wv[q] = nw[q]; }
        }
#pragma unroll
        for (int q = 0; q < 4; q++) {
            a0 = fmaf(bf_lo(v[q].x), wv[q], a0);
            a1 = fmaf(bf_hi(v[q].x), wv[q], a1);
            a2 = fmaf(bf_lo(v[q].y), wv[q], a2);
            a3 = fmaf(bf_hi(v[q].y), wv[q], a3);
        }
    }
    // combine even/odd halves
    a0 += __shfl_xor(a0, 32);
    a1 += __shfl_xor(a1, 32);
    a2 += __shfl_xor(a2, 32);
    a3 += __shfl_xor(a3, 32);
    if (half == 0) {
        float4 bv = *(const float4*)&bias[c4];
        u32 w0 = (u32)f2bf(fmaxf(a0 + bv.x, 0.f)) | ((u32)f2bf(fmaxf(a1 + bv.y, 0.f)) << 16);
        u32 w1 = (u32)f2bf(fmaxf(a2 + bv.z, 0.f)) | ((u32)f2bf(fmaxf(a3 + bv.w, 0.f)) << 16);
        *(uint2*)&out[(size_t)i * HD1 + c4] = make_uint2(w0, w1);
    }
}

// ---------- GEMM2: agg1[N,128]bf16 @ Wt2[64][128]bf16 -> h2 [N,64]bf16, MFMA ----------
__global__ __launch_bounds__(256) void k_gemm2(const unsigned short* __restrict__ A,
                                               const unsigned short* __restrict__ Wt2,
                                               unsigned short* __restrict__ H, int N) {
    __shared__ unsigned short As[128 * 128];  // swizzled [row][k]
    __shared__ unsigned short Bs[64 * 128];   // swizzled [col][k]
    const int tid = threadIdx.x;
    const int lane = tid & 63;
    const int wid = tid >> 6;
    const int brow = blockIdx.x * 128;
    const int wr0 = wid * 32;

#pragma unroll
    for (int p = 0; p < 8; p++) {
        int chunk = (wid * 8 + p) * 64 + lane;
        int r = chunk >> 4;                 // 16 chunks per 128-elem row
        int kcs = chunk & 15;
        int kc = kcs ^ (r & 7);             // inverse swizzle on source
        const unsigned short* src = &A[(size_t)(brow + r) * HD1 + kc * 8];
        unsigned short* dst = &As[(wid * 8 + p) * 512];
        __builtin_amdgcn_global_load_lds(
            (const __attribute__((address_space(1))) u32*)(const void*)src,
            (__attribute__((address_space(3))) u32*)(void*)dst, 16, 0, 0);
    }
#pragma unroll
    for (int p = 0; p < 4; p++) {
        int chunk = (wid * 4 + p) * 64 + lane;
        int c = chunk >> 4;
        int kcs = chunk & 15;
        int kc = kcs ^ (c & 7);
        const unsigned short* src = &Wt2[(size_t)c * HD1 + kc * 8];
        unsigned short* dst = &Bs[(wid * 4 + p) * 512];
        __builtin_amdgcn_global_load_lds(
            (const __attribute__((address_space(1))) u32*)(const void*)src,
            (__attribute__((address_space(3))) u32*)(void*)dst, 16, 0, 0);
    }
    __syncthreads();

    f32x4 acc[2][4];
#pragma unroll
    for (int i = 0; i < 2; i++)
#pragma unroll
        for (int j = 0; j < 4; j++) acc[i][j] = (f32x4){0.f, 0.f, 0.f, 0.f};

#pragma unroll
    for (int kk = 0; kk < 4; kk++) {
        const int kel = kk * 32 + (lane >> 4) * 8;
        bf16x8 a[2], b[4];
#pragma unroll
        for (int mi = 0; mi < 2; mi++)
            a[mi] = *(const bf16x8*)&As[elem_off128(wr0 + mi * 16 + (lane & 15), kel)];
#pragma unroll
        for (int ni = 0; ni < 4; ni++)
            b[ni] = *(const bf16x8*)&Bs[elem_off128(ni * 16 + (lane & 15), kel)];
#pragma unroll
        for (int mi = 0; mi < 2; mi++)
#pragma unroll
            for (int ni = 0; ni < 4; ni++)
                acc[mi][ni] = __builtin_amdgcn_mfma_f32_16x16x32_bf16(
                    a[mi], b[ni], acc[mi][ni], 0, 0, 0);
    }

#pragma unroll
    for (int mi = 0; mi < 2; mi++) {
#pragma unroll
        for (int reg = 0; reg < 4; reg++) {
            int grow = brow + wr0 + mi * 16 + (lane >> 4) * 4 + reg;
            if (grow < N) {
#pragma unroll
                for (int ni = 0; ni < 4; ni++) {
                    int gcol = ni * 16 + (lane & 15);
                    H[(size_t)grow * HD2 + gcol] = f2bf(acc[mi][ni][reg]);
                }
            }
        }
    }
}

// ---------- gather layer2: paired half-wave edges, 2-deep pipeline, f32 out ----------
__global__ __launch_bounds__(256) void k_gather2(const unsigned short* __restrict__ h,
                                                 const int* __restrict__ rowptr,
                                                 const int* __restrict__ col,
                                                 const float* __restrict__ wgt,
                                                 const float* __restrict__ dinv,
                                                 const float* __restrict__ bias,
                                                 float* __restrict__ out, int N) {
    const int i = (blockIdx.x * 256 + threadIdx.x) >> 6;
    const int lane = threadIdx.x & 63;
    if (i >= N) return;
    const int half = lane >> 5;
    const int c2 = (lane & 31) * 2;           // my 2 columns
    const float di = dinv[i];
    const unsigned short* hc = h + c2;

    float a0 = 0.f, a1 = 0.f;
    if (half == 0) {
        u32 sv = *(const u32*)&hc[(size_t)i * HD2];
        float s = di * di;
        a0 = bf_lo(sv) * s; a1 = bf_hi(sv) * s;
    }
    const int beg = rowptr[i], end = rowptr[i + 1];
    for (int p0 = beg; p0 < end; p0 += 64) {
        int idx = p0 + lane;
        bool okl = idx < end;
        int myj = okl ? col[idx] : i;
        float myw = okl ? wgt[idx] : 0.f;
        const int cnt8 = (min(64, end - p0) + 7) & ~7;
        u32 v[4]; float wv[4];
#pragma unroll
        for (int q = 0; q < 4; q++) {
            int e = 2 * q + half;
            int j = __shfl(myj, e);
            wv[q] = __shfl(myw, e);
            v[q] = *(const u32*)&hc[(size_t)j * HD2];
        }
        for (int k = 8; k < cnt8; k += 8) {
            u32 nv[4]; float nw[4];
#pragma unroll
            for (int q = 0; q < 4; q++) {
                int e = k + 2 * q + half;
                int j = __shfl(myj, e);
                nw[q] = __shfl(myw, e);
                nv[q] = *(const u32*)&hc[(size_t)j * HD2];
            }
#pragma unroll
            for (int q = 0; q < 4; q++) {
                a0 = fmaf(bf_lo(v[q]), wv[q], a0);
                a1 = fmaf(bf_hi(v[q]), wv[q], a1);
            }
#pragma unroll
            for (int q = 0; q < 4; q++) { v[q] = nv[q]; wv[q] = nw[q]; }
        }
#pragma unroll
        for (int q = 0; q < 4; q++) {
            a0 = fmaf(bf_lo(v[q]), wv[q], a0);
            a1 = fmaf(bf_hi(v[q]), wv[q], a1);
        }
    }
    a0 += __shfl_xor(a0, 32);
    a1 += __shfl_xor(a1, 32);
    if (half == 0) {
        float2 bv = *(const float2*)&bias[c2];
        float2 r = make_float2(fmaxf(a0 + bv.x, 0.f), fmaxf(a1 + bv.y, 0.f));
        *(float2*)&out[(size_t)i * HD2 + c2] = r;
    }
}

extern "C" void kernel_launch(void* const* d_in, const int* in_sizes, int n_in,
                              void* d_out, int out_size, void* d_ws, size_t ws_size,
                              hipStream_t stream) {
    const float* x  = (const float*)d_in[0];
    const int*   ei = (const int*)d_in[1];
    const float* W1 = (const float*)d_in[2];
    const float* b1 = (const float*)d_in[3];
    const float* W2 = (const float*)d_in[4];
    const float* b2 = (const float*)d_in[5];
    float* out = (float*)d_out;

    const int N = in_sizes[0] / IN_DIM;     // 50000
    const int E = in_sizes[1] / 2;          // 800000
    const int* src = ei;
    const int* dst = ei + E;

    // workspace layout (256B aligned)
    char* w = (char*)d_ws;
    size_t off = 0;
    auto alloc = [&](size_t bytes) -> void* {
        void* p = w + off;
        off = (off + bytes + 255) & ~(size_t)255;
        return p;
    };
    int*   deg    = (int*)alloc((size_t)N * 4);   // deg+fill adjacent: single memset
    int*   fill   = (int*)alloc((size_t)N * 4);
    int*   rowptr = (int*)alloc((size_t)(N + 1) * 4);
    int*   bsum   = (int*)alloc(1024 * 4);
    int*   col    = (int*)alloc((size_t)E * 4);
    float* wgt    = (float*)alloc((size_t)E * 4);
    float* dinv   = (float*)alloc((size_t)N * 4);
    unsigned short* Wt  = (unsigned short*)alloc((size_t)IN_DIM * HD1 * 2);
    unsigned short* Wt2 = (unsigned short*)alloc((size_t)HD2 * HD1 * 2);
    unsigned short* h1  = (unsigned short*)alloc((size_t)N * HD1 * 2);          // bf16
    unsigned short* agg1= (unsigned short*)alloc((size_t)(N + 128) * HD1 * 2);  // bf16, padded
    unsigned short* h2  = h1;  // h1 dead after gather1; N*64*2 <= N*128*2

    // one memset spanning deg..fill (adjacent allocations)
    size_t zero_span = (size_t)((char*)fill - (char*)deg) + (size_t)N * 4;
    hipMemsetAsync(deg, 0, zero_span, stream);

    const int nb = (N + 255) / 256;
    const int eb = (E + 255) / 256;

    k_prep<<<eb, 256, 0, stream>>>(dst, E, deg, W1, Wt, W2, Wt2);
    k_dinv_bsum<<<nb, 256, 0, stream>>>(deg, N, dinv, bsum);
    k_scan_bsum<<<1, 1024, 0, stream>>>(bsum, nb);
    k_scan_final<<<nb, 256, 0, stream>>>(deg, N, bsum, rowptr);
    k_fill<<<eb, 256, 0, stream>>>(src, dst, E, rowptr, dinv, fill, col, wgt);

    k_gemm1<<<(N + 127) / 128, 256, 0, stream>>>(x, Wt, h1, N);
    k_gather1<<<(N * 64 + 255) / 256, 256, 0, stream>>>(h1, rowptr, col, wgt, dinv, b1, agg1, N);
    k_gemm2<<<(N + 127) / 128, 256, 0, stream>>>(agg1, Wt2, h2, N);
    k_gather2<<<(N * 64 + 255) / 256, 256, 0, stream>>>(h2, rowptr, col, wgt, dinv, b2, out, N);
}

// Round 6
// 169.227 us; speedup vs baseline: 2.5302x; 1.0602x over previous
//
#include <hip/hip_runtime.h>

// 2-layer GCN: h = relu(Anorm @ (x@W1) + b1); out = relu(Anorm @ (h@W2) + b2)
// Round 6: MEGA kernel overlaps gemm1 with CSR fill (disjoint block ranges);
// wgt array removed (recomputed from L2-resident dinv in gathers, bit-identical).

constexpr int IN_DIM = 512;
constexpr int HD1 = 128;
constexpr int HD2 = 64;

typedef __attribute__((ext_vector_type(8))) short bf16x8;
typedef __attribute__((ext_vector_type(8))) unsigned short u16x8;
typedef __attribute__((ext_vector_type(4))) float f32x4;
typedef unsigned int u32;

__device__ inline unsigned short f2bf(float f) {
    u32 u = __builtin_bit_cast(u32, f);
    return (unsigned short)((u + 0x7fffu + ((u >> 16) & 1u)) >> 16);
}
__device__ inline float bf_lo(u32 v) { return __builtin_bit_cast(float, v << 16); }
__device__ inline float bf_hi(u32 v) { return __builtin_bit_cast(float, v & 0xffff0000u); }

// swizzled LDS element offset, [row][64] bf16 tiles
__device__ inline int elem_off(int row, int k) {
    return (row << 6) + (k ^ ((row & 7) << 3));
}
// swizzled LDS element offset, [row][128] bf16 tiles
__device__ inline int elem_off128(int row, int k) {
    return (row << 7) + (k ^ ((row & 7) << 3));
}

// ---------- fused prep: deg atomics + W1^T bf16 + W2^T bf16 ----------
__global__ __launch_bounds__(256) void k_prep(const int* __restrict__ dst, int E,
                                              int* __restrict__ deg,
                                              const float* __restrict__ W1,
                                              unsigned short* __restrict__ Wt,
                                              const float* __restrict__ W2,
                                              unsigned short* __restrict__ Wt2) {
    int id = blockIdx.x * 256 + threadIdx.x;
    if (id < E) atomicAdd(&deg[dst[id]], 1);
    if (id < IN_DIM * HD1) {                    // 65536: W1^T
        int n = id >> 9, k = id & 511;
        Wt[id] = f2bf(W1[k * HD1 + n]);
    }
    if (id < HD1 * HD2) {                       // 8192: W2^T
        int n = id >> 7, k = id & 127;
        Wt2[id] = f2bf(W2[k * HD2 + n]);
    }
}

// ---------- dinv + per-block degree sums (fused) ----------
__global__ __launch_bounds__(256) void k_dinv_bsum(const int* __restrict__ deg, int N,
                                                   float* __restrict__ dinv,
                                                   int* __restrict__ bsum) {
    __shared__ int s[256];
    int t = threadIdx.x;
    int i = blockIdx.x * 256 + t;
    int d = (i < N) ? deg[i] : 0;
    if (i < N) dinv[i] = rsqrtf((float)(d + 1));  // +1 = self loop
    s[t] = d;
    __syncthreads();
    for (int st = 128; st > 0; st >>= 1) {
        if (t < st) s[t] += s[t + st];
        __syncthreads();
    }
    if (t == 0) bsum[blockIdx.x] = s[0];
}

__global__ __launch_bounds__(1024) void k_scan_bsum(int* __restrict__ bsum, int nb) {
    __shared__ int s[1024];
    int t = threadIdx.x;
    s[t] = (t < nb) ? bsum[t] : 0;
    __syncthreads();
    for (int off = 1; off < 1024; off <<= 1) {
        int v = (t >= off) ? s[t - off] : 0;
        __syncthreads();
        s[t] += v;
        __syncthreads();
    }
    if (t < nb) bsum[t] = (t == 0) ? 0 : s[t - 1];  // exclusive
}

__global__ __launch_bounds__(256) void k_scan_final(const int* __restrict__ deg, int N,
                                                    const int* __restrict__ bsum,
                                                    int* __restrict__ rowptr) {
    __shared__ int s[256];
    int t = threadIdx.x;
    int i = blockIdx.x * 256 + t;
    int v = (i < N) ? deg[i] : 0;
    s[t] = v;
    __syncthreads();
    for (int off = 1; off < 256; off <<= 1) {
        int u = (t >= off) ? s[t - off] : 0;
        __syncthreads();
        s[t] += u;
        __syncthreads();
    }
    int incl = s[t] + bsum[blockIdx.x];
    if (i < N) rowptr[i] = incl - v;
    if (i == N - 1) rowptr[N] = incl;
}

// ---------- MEGA: blocks [0,gemmBlocks) = gemm1; rest = CSR fill ----------
__global__ __launch_bounds__(256) void k_mega(const float* __restrict__ X,
                                              const unsigned short* __restrict__ Wt,
                                              unsigned short* __restrict__ H, int N,
                                              int gemmBlocks,
                                              const int* __restrict__ src,
                                              const int* __restrict__ dst, int E,
                                              const int* __restrict__ rowptr,
                                              int* __restrict__ fill,
                                              int* __restrict__ col) {
    __shared__ unsigned short As[128 * 64];  // x tile, swizzled [row][k]
    __shared__ unsigned short Bs[128 * 64];  // W tile, swizzled [col][k]

    if (blockIdx.x >= gemmBlocks) {
        // ---------------- CSR fill (grid-strided) ----------------
        int stride = (gridDim.x - gemmBlocks) * 256;
        for (int e = (blockIdx.x - gemmBlocks) * 256 + threadIdx.x; e < E; e += stride) {
            int s = src[e], d = dst[e];
            int pos = rowptr[d] + atomicAdd(&fill[d], 1);
            col[pos] = s;
        }
        return;
    }

    // ---------------- GEMM1 ----------------
    const int tid = threadIdx.x;
    const int lane = tid & 63;
    const int wid = tid >> 6;
    const int brow = blockIdx.x * 128;
    const int wr0 = (wid >> 1) * 64;
    const int wc0 = (wid & 1) * 64;
    const bool full = (brow + 128 <= N);

    f32x4 acc[4][4];
#pragma unroll
    for (int i = 0; i < 4; i++)
#pragma unroll
        for (int j = 0; j < 4; j++) acc[i][j] = (f32x4){0.f, 0.f, 0.f, 0.f};

    for (int kt = 0; kt < IN_DIM / 64; kt++) {
        const int k0 = kt * 64;
        // issue B first: global_load_lds streams while A-staging runs
#pragma unroll
        for (int p = 0; p < 4; p++) {
            int chunk = (wid * 4 + p) * 64 + lane;  // 16B chunk id
            int n = chunk >> 3;
            int kcs = chunk & 7;
            int kc = kcs ^ (n & 7);                 // inverse swizzle on source
            const unsigned short* srcp = &Wt[(size_t)n * IN_DIM + k0 + kc * 8];
            unsigned short* dstp = &Bs[(wid * 4 + p) * 512];  // wave-uniform base
            __builtin_amdgcn_global_load_lds(
                (const __attribute__((address_space(1))) u32*)(const void*)srcp,
                (__attribute__((address_space(3))) u32*)(void*)dstp, 16, 0, 0);
        }
        // stage A: 128 rows x 64 k, f32 -> bf16, reg-staged
#pragma unroll
        for (int p = 0; p < 4; p++) {
            int chunk = tid + p * 256;     // 1024 chunks of 8 elems
            int r = chunk >> 3;
            int kc = chunk & 7;
            const float* xp = &X[(size_t)(brow + r) * IN_DIM + k0 + kc * 8];
            float4 v0, v1;
            if (full || (brow + r) < N) {
                v0 = *(const float4*)xp;
                v1 = *(const float4*)(xp + 4);
            } else {
                v0 = make_float4(0.f, 0.f, 0.f, 0.f); v1 = v0;
            }
            u16x8 w;
            w[0] = f2bf(v0.x); w[1] = f2bf(v0.y); w[2] = f2bf(v0.z); w[3] = f2bf(v0.w);
            w[4] = f2bf(v1.x); w[5] = f2bf(v1.y); w[6] = f2bf(v1.z); w[7] = f2bf(v1.w);
            *(u16x8*)&As[elem_off(r, kc * 8)] = w;
        }
        __syncthreads();

#pragma unroll
        for (int kk = 0; kk < 2; kk++) {
            const int kel = kk * 32 + (lane >> 4) * 8;
            bf16x8 a[4], b[4];
#pragma unroll
            for (int mi = 0; mi < 4; mi++)
                a[mi] = *(const bf16x8*)&As[elem_off(wr0 + mi * 16 + (lane & 15), kel)];
#pragma unroll
            for (int ni = 0; ni < 4; ni++)
                b[ni] = *(const bf16x8*)&Bs[elem_off(wc0 + ni * 16 + (lane & 15), kel)];
#pragma unroll
            for (int mi = 0; mi < 4; mi++)
#pragma unroll
                for (int ni = 0; ni < 4; ni++)
                    acc[mi][ni] = __builtin_amdgcn_mfma_f32_16x16x32_bf16(
                        a[mi], b[ni], acc[mi][ni], 0, 0, 0);
        }
        __syncthreads();
    }

#pragma unroll
    for (int mi = 0; mi < 4; mi++) {
#pragma unroll
        for (int reg = 0; reg < 4; reg++) {
            int grow = brow + wr0 + mi * 16 + (lane >> 4) * 4 + reg;
            if (grow < N) {
#pragma unroll
                for (int ni = 0; ni < 4; ni++) {
                    int gcol = wc0 + ni * 16 + (lane & 15);
                    H[(size_t)grow * HD1 + gcol] = f2bf(acc[mi][ni][reg]);
                }
            }
        }
    }
}

// ---------- gather layer1: paired half-wave edges, weights from L2-resident dinv ----------
__global__ __launch_bounds__(256) void k_gather1(const unsigned short* __restrict__ h,
                                                 const int* __restrict__ rowptr,
                                                 const int* __restrict__ col,
                                                 const float* __restrict__ dinv,
                                                 const float* __restrict__ bias,
                                                 unsigned short* __restrict__ out, int N) {
    const int i = (blockIdx.x * 256 + threadIdx.x) >> 6;
    const int lane = threadIdx.x & 63;
    if (i >= N) return;
    const int half = lane >> 5;
    const int c4 = (lane & 31) * 4;           // my 4 columns
    const float di = dinv[i];
    const unsigned short* hc = h + c4;

    float a0 = 0.f, a1 = 0.f, a2 = 0.f, a3 = 0.f;
    if (half == 0) {  // self-loop term counted once
        uint2 sv = *(const uint2*)&hc[(size_t)i * HD1];
        float s = di * di;
        a0 = bf_lo(sv.x) * s; a1 = bf_hi(sv.x) * s;
        a2 = bf_lo(sv.y) * s; a3 = bf_hi(sv.y) * s;
    }
    const int beg = rowptr[i], end = rowptr[i + 1];
    for (int p0 = beg; p0 < end; p0 += 64) {
        int idx = p0 + lane;
        bool okl = idx < end;
        int myj = okl ? col[idx] : i;
        float mydj = okl ? dinv[myj] : 0.f;   // dinv: 200KB, L2-resident
        const int cnt8 = (min(64, end - p0) + 7) & ~7;
        uint2 v[4]; float wv[4];
#pragma unroll
        for (int q = 0; q < 4; q++) {          // prologue: edges 0..7
            int e = 2 * q + half;
            int j = __shfl(myj, e);
            wv[q] = __shfl(mydj, e) * di;
            v[q] = *(const uint2*)&hc[(size_t)j * HD1];
        }
        for (int k = 8; k < cnt8; k += 8) {
            uint2 nv[4]; float nw[4];
#pragma unroll
            for (int q = 0; q < 4; q++) {      // issue next 8 gathers first
                int e = k + 2 * q + half;
                int j = __shfl(myj, e);
                nw[q] = __shfl(mydj, e) * di;
                nv[q] = *(const uint2*)&hc[(size_t)j * HD1];
            }
#pragma unroll
            for (int q = 0; q < 4; q++) {      // consume previous 8
                a0 = fmaf(bf_lo(v[q].x), wv[q], a0);
                a1 = fmaf(bf_hi(v[q].x), wv[q], a1);
                a2 = fmaf(bf_lo(v[q].y), wv[q], a2);
                a3 = fmaf(bf_hi(v[q].y), wv[q], a3);
            }
#pragma unroll
            for (int q = 0; q < 4; q++) { v[q] = nv[q]; wv[q] = nw[q]; }
        }
#pragma unroll
        for (int q = 0; q < 4; q++) {
            a0 = fmaf(bf_lo(v[q].x), wv[q], a0);
            a1 = fmaf(bf_hi(v[q].x), wv[q], a1);
            a2 = fmaf(bf_lo(v[q].y), wv[q], a2);
            a3 = fmaf(bf_hi(v[q].y), wv[q], a3);
        }
    }
    // combine even/odd halves
    a0 += __shfl_xor(a0, 32);
    a1 += __shfl_xor(a1, 32);
    a2 += __shfl_xor(a2, 32);
    a3 += __shfl_xor(a3, 32);
    if (half == 0) {
        float4 bv = *(const float4*)&bias[c4];
        u32 w0 = (u32)f2bf(fmaxf(a0 + bv.x, 0.f)) | ((u32)f2bf(fmaxf(a1 + bv.y, 0.f)) << 16);
        u32 w1 = (u32)f2bf(fmaxf(a2 + bv.z, 0.f)) | ((u32)f2bf(fmaxf(a3 + bv.w, 0.f)) << 16);
        *(uint2*)&out[(size_t)i * HD1 + c4] = make_uint2(w0, w1);
    }
}

// ---------- GEMM2: agg1[N,128]bf16 @ Wt2[64][128]bf16 -> h2 [N,64]bf16, MFMA ----------
__global__ __launch_bounds__(256) void k_gemm2(const unsigned short* __restrict__ A,
                                               const unsigned short* __restrict__ Wt2,
                                               unsigned short* __restrict__ H, int N) {
    __shared__ unsigned short As[128 * 128];  // swizzled [row][k]
    __shared__ unsigned short Bs[64 * 128];   // swizzled [col][k]
    const int tid = threadIdx.x;
    const int lane = tid & 63;
    const int wid = tid >> 6;
    const int brow = blockIdx.x * 128;
    const int wr0 = wid * 32;

#pragma unroll
    for (int p = 0; p < 8; p++) {
        int chunk = (wid * 8 + p) * 64 + lane;
        int r = chunk >> 4;                 // 16 chunks per 128-elem row
        int kcs = chunk & 15;
        int kc = kcs ^ (r & 7);             // inverse swizzle on source
        const unsigned short* src = &A[(size_t)(brow + r) * HD1 + kc * 8];
        unsigned short* dst = &As[(wid * 8 + p) * 512];
        __builtin_amdgcn_global_load_lds(
            (const __attribute__((address_space(1))) u32*)(const void*)src,
            (__attribute__((address_space(3))) u32*)(void*)dst, 16, 0, 0);
    }
#pragma unroll
    for (int p = 0; p < 4; p++) {
        int chunk = (wid * 4 + p) * 64 + lane;
        int c = chunk >> 4;
        int kcs = chunk & 15;
        int kc = kcs ^ (c & 7);
        const unsigned short* src = &Wt2[(size_t)c * HD1 + kc * 8];
        unsigned short* dst = &Bs[(wid * 4 + p) * 512];
        __builtin_amdgcn_global_load_lds(
            (const __attribute__((address_space(1))) u32*)(const void*)src,
            (__attribute__((address_space(3))) u32*)(void*)dst, 16, 0, 0);
    }
    __syncthreads();

    f32x4 acc[2][4];
#pragma unroll
    for (int i = 0; i < 2; i++)
#pragma unroll
        for (int j = 0; j < 4; j++) acc[i][j] = (f32x4){0.f, 0.f, 0.f, 0.f};

#pragma unroll
    for (int kk = 0; kk < 4; kk++) {
        const int kel = kk * 32 + (lane >> 4) * 8;
        bf16x8 a[2], b[4];
#pragma unroll
        for (int mi = 0; mi < 2; mi++)
            a[mi] = *(const bf16x8*)&As[elem_off128(wr0 + mi * 16 + (lane & 15), kel)];
#pragma unroll
        for (int ni = 0; ni < 4; ni++)
            b[ni] = *(const bf16x8*)&Bs[elem_off128(ni * 16 + (lane & 15), kel)];
#pragma unroll
        for (int mi = 0; mi < 2; mi++)
#pragma unroll
            for (int ni = 0; ni < 4; ni++)
                acc[mi][ni] = __builtin_amdgcn_mfma_f32_16x16x32_bf16(
                    a[mi], b[ni], acc[mi][ni], 0, 0, 0);
    }

#pragma unroll
    for (int mi = 0; mi < 2; mi++) {
#pragma unroll
        for (int reg = 0; reg < 4; reg++) {
            int grow = brow + wr0 + mi * 16 + (lane >> 4) * 4 + reg;
            if (grow < N) {
#pragma unroll
                for (int ni = 0; ni < 4; ni++) {
                    int gcol = ni * 16 + (lane & 15);
                    H[(size_t)grow * HD2 + gcol] = f2bf(acc[mi][ni][reg]);
                }
            }
        }
    }
}

// ---------- gather layer2: paired half-wave edges, f32 out ----------
__global__ __launch_bounds__(256) void k_gather2(const unsigned short* __restrict__ h,
                                                 const int* __restrict__ rowptr,
                                                 const int* __restrict__ col,
                                                 const float* __restrict__ dinv,
                                                 const float* __restrict__ bias,
                                                 float* __restrict__ out, int N) {
    const int i = (blockIdx.x * 256 + threadIdx.x) >> 6;
    const int lane = threadIdx.x & 63;
    if (i >= N) return;
    const int half = lane >> 5;
    const int c2 = (lane & 31) * 2;           // my 2 columns
    const float di = dinv[i];
    const unsigned short* hc = h + c2;

    float a0 = 0.f, a1 = 0.f;
    if (half == 0) {
        u32 sv = *(const u32*)&hc[(size_t)i * HD2];
        float s = di * di;
        a0 = bf_lo(sv) * s; a1 = bf_hi(sv) * s;
    }
    const int beg = rowptr[i], end = rowptr[i + 1];
    for (int p0 = beg; p0 < end; p0 += 64) {
        int idx = p0 + lane;
        bool okl = idx < end;
        int myj = okl ? col[idx] : i;
        float mydj = okl ? dinv[myj] : 0.f;
        const int cnt8 = (min(64, end - p0) + 7) & ~7;
        u32 v[4]; float wv[4];
#pragma unroll
        for (int q = 0; q < 4; q++) {
            int e = 2 * q + half;
            int j = __shfl(myj, e);
            wv[q] = __shfl(mydj, e) * di;
            v[q] = *(const u32*)&hc[(size_t)j * HD2];
        }
        for (int k = 8; k < cnt8; k += 8) {
            u32 nv[4]; float nw[4];
#pragma unroll
            for (int q = 0; q < 4; q++) {
                int e = k + 2 * q + half;
                int j = __shfl(myj, e);
                nw[q] = __shfl(mydj, e) * di;
                nv[q] = *(const u32*)&hc[(size_t)j * HD2];
            }
#pragma unroll
            for (int q = 0; q < 4; q++) {
                a0 = fmaf(bf_lo(v[q]), wv[q], a0);
                a1 = fmaf(bf_hi(v[q]), wv[q], a1);
            }
#pragma unroll
            for (int q = 0; q < 4; q++) { v[q] = nv[q]; wv[q] = nw[q]; }
        }
#pragma unroll
        for (int q = 0; q < 4; q++) {
            a0 = fmaf(bf_lo(v[q]), wv[q], a0);
            a1 = fmaf(bf_hi(v[q]), wv[q], a1);
        }
    }
    a0 += __shfl_xor(a0, 32);
    a1 += __shfl_xor(a1, 32);
    if (half == 0) {
        float2 bv = *(const float2*)&bias[c2];
        float2 r = make_float2(fmaxf(a0 + bv.x, 0.f), fmaxf(a1 + bv.y, 0.f));
        *(float2*)&out[(size_t)i * HD2 + c2] = r;
    }
}

extern "C" void kernel_launch(void* const* d_in, const int* in_sizes, int n_in,
                              void* d_out, int out_size, void* d_ws, size_t ws_size,
                              hipStream_t stream) {
    const float* x  = (const float*)d_in[0];
    const int*   ei = (const int*)d_in[1];
    const float* W1 = (const float*)d_in[2];
    const float* b1 = (const float*)d_in[3];
    const float* W2 = (const float*)d_in[4];
    const float* b2 = (const float*)d_in[5];
    float* out = (float*)d_out;

    const int N = in_sizes[0] / IN_DIM;     // 50000
    const int E = in_sizes[1] / 2;          // 800000
    const int* src = ei;
    const int* dst = ei + E;

    // workspace layout (256B aligned)
    char* w = (char*)d_ws;
    size_t off = 0;
    auto alloc = [&](size_t bytes) -> void* {
        void* p = w + off;
        off = (off + bytes + 255) & ~(size_t)255;
        return p;
    };
    int*   deg    = (int*)alloc((size_t)N * 4);   // deg+fill adjacent: single memset
    int*   fill   = (int*)alloc((size_t)N * 4);
    int*   rowptr = (int*)alloc((size_t)(N + 1) * 4);
    int*   bsum   = (int*)alloc(1024 * 4);
    int*   col    = (int*)alloc((size_t)E * 4);
    float* dinv   = (float*)alloc((size_t)N * 4);
    unsigned short* Wt  = (unsigned short*)alloc((size_t)IN_DIM * HD1 * 2);
    unsigned short* Wt2 = (unsigned short*)alloc((size_t)HD2 * HD1 * 2);
    unsigned short* h1  = (unsigned short*)alloc((size_t)N * HD1 * 2);          // bf16
    unsigned short* agg1= (unsigned short*)alloc((size_t)(N + 128) * HD1 * 2);  // bf16, padded
    unsigned short* h2  = h1;  // h1 dead after gather1; N*64*2 <= N*128*2

    // one memset spanning deg..fill (adjacent allocations)
    size_t zero_span = (size_t)((char*)fill - (char*)deg) + (size_t)N * 4;
    hipMemsetAsync(deg, 0, zero_span, stream);

    const int nb = (N + 255) / 256;
    const int eb = (E + 255) / 256;
    const int gemmBlocks = (N + 127) / 128;   // 391
    const int fillBlocks = 512;

    k_prep<<<eb, 256, 0, stream>>>(dst, E, deg, W1, Wt, W2, Wt2);
    k_dinv_bsum<<<nb, 256, 0, stream>>>(deg, N, dinv, bsum);
    k_scan_bsum<<<1, 1024, 0, stream>>>(bsum, nb);
    k_scan_final<<<nb, 256, 0, stream>>>(deg, N, bsum, rowptr);

    k_mega<<<gemmBlocks + fillBlocks, 256, 0, stream>>>(
        x, Wt, h1, N, gemmBlocks, src, dst, E, rowptr, fill, col);

    k_gather1<<<(N * 64 + 255) / 256, 256, 0, stream>>>(h1, rowptr, col, dinv, b1, agg1, N);
    k_gemm2<<<(N + 127) / 128, 256, 0, stream>>>(agg1, Wt2, h2, N);
    k_gather2<<<(N * 64 + 255) / 256, 256, 0, stream>>>(h2, rowptr, col, dinv, b2, out, N);
}

// Round 7
// 147.339 us; speedup vs baseline: 2.9061x; 1.1486x over previous
//
#include <hip/hip_runtime.h>

// 2-layer GCN: h = relu(Anorm @ (x@W1) + b1); out = relu(Anorm @ (h@W2) + b2)
// Round 7: atomic-free CSR fill (rank captured from prep's degree atomic),
// scan_bsum fused into scan_final. Mega overlaps gemm1 with the cheap fill.

constexpr int IN_DIM = 512;
constexpr int HD1 = 128;
constexpr int HD2 = 64;

typedef __attribute__((ext_vector_type(8))) short bf16x8;
typedef __attribute__((ext_vector_type(8))) unsigned short u16x8;
typedef __attribute__((ext_vector_type(4))) float f32x4;
typedef unsigned int u32;

__device__ inline unsigned short f2bf(float f) {
    u32 u = __builtin_bit_cast(u32, f);
    return (unsigned short)((u + 0x7fffu + ((u >> 16) & 1u)) >> 16);
}
__device__ inline float bf_lo(u32 v) { return __builtin_bit_cast(float, v << 16); }
__device__ inline float bf_hi(u32 v) { return __builtin_bit_cast(float, v & 0xffff0000u); }

// swizzled LDS element offset, [row][64] bf16 tiles
__device__ inline int elem_off(int row, int k) {
    return (row << 6) + (k ^ ((row & 7) << 3));
}
// swizzled LDS element offset, [row][128] bf16 tiles
__device__ inline int elem_off128(int row, int k) {
    return (row << 7) + (k ^ ((row & 7) << 3));
}

// ---------- fused prep: deg atomics (rank captured) + W1^T bf16 + W2^T bf16 ----------
__global__ __launch_bounds__(256) void k_prep(const int* __restrict__ dst, int E,
                                              int* __restrict__ deg,
                                              int* __restrict__ rank,
                                              const float* __restrict__ W1,
                                              unsigned short* __restrict__ Wt,
                                              const float* __restrict__ W2,
                                              unsigned short* __restrict__ Wt2) {
    int id = blockIdx.x * 256 + threadIdx.x;
    if (id < E) rank[id] = atomicAdd(&deg[dst[id]], 1);
    if (id < IN_DIM * HD1) {                    // 65536: W1^T
        int n = id >> 9, k = id & 511;
        Wt[id] = f2bf(W1[k * HD1 + n]);
    }
    if (id < HD1 * HD2) {                       // 8192: W2^T
        int n = id >> 7, k = id & 127;
        Wt2[id] = f2bf(W2[k * HD2 + n]);
    }
}

// ---------- dinv + per-block degree sums (fused) ----------
__global__ __launch_bounds__(256) void k_dinv_bsum(const int* __restrict__ deg, int N,
                                                   float* __restrict__ dinv,
                                                   int* __restrict__ bsum) {
    __shared__ int s[256];
    int t = threadIdx.x;
    int i = blockIdx.x * 256 + t;
    int d = (i < N) ? deg[i] : 0;
    if (i < N) dinv[i] = rsqrtf((float)(d + 1));  // +1 = self loop
    s[t] = d;
    __syncthreads();
    for (int st = 128; st > 0; st >>= 1) {
        if (t < st) s[t] += s[t + st];
        __syncthreads();
    }
    if (t == 0) bsum[blockIdx.x] = s[0];
}

// ---------- scan_final with fused bsum scan (nb <= 256) ----------
__global__ __launch_bounds__(256) void k_scan_final(const int* __restrict__ deg, int N,
                                                    const int* __restrict__ bsum, int nb,
                                                    int* __restrict__ rowptr) {
    __shared__ int sb[256];
    __shared__ int s[256];
    int t = threadIdx.x;
    // redundant per-block scan of bsum (196 entries)
    sb[t] = (t < nb) ? bsum[t] : 0;
    __syncthreads();
    for (int off = 1; off < 256; off <<= 1) {
        int v = (t >= off) ? sb[t - off] : 0;
        __syncthreads();
        sb[t] += v;
        __syncthreads();
    }
    int base = (blockIdx.x == 0) ? 0 : sb[blockIdx.x - 1];

    int i = blockIdx.x * 256 + t;
    int v = (i < N) ? deg[i] : 0;
    s[t] = v;
    __syncthreads();
    for (int off = 1; off < 256; off <<= 1) {
        int u = (t >= off) ? s[t - off] : 0;
        __syncthreads();
        s[t] += u;
        __syncthreads();
    }
    int incl = s[t] + base;
    if (i < N) rowptr[i] = incl - v;
    if (i == N - 1) rowptr[N] = incl;
}

// ---------- MEGA: blocks [0,gemmBlocks) = gemm1; rest = atomic-free CSR fill ----------
__global__ __launch_bounds__(256) void k_mega(const float* __restrict__ X,
                                              const unsigned short* __restrict__ Wt,
                                              unsigned short* __restrict__ H, int N,
                                              int gemmBlocks,
                                              const int* __restrict__ src,
                                              const int* __restrict__ dst, int E,
                                              const int* __restrict__ rowptr,
                                              const int* __restrict__ rank,
                                              int* __restrict__ col) {
    __shared__ unsigned short As[128 * 64];  // x tile, swizzled [row][k]
    __shared__ unsigned short Bs[128 * 64];  // W tile, swizzled [col][k]

    if (blockIdx.x >= gemmBlocks) {
        // ---------------- CSR fill, no atomics ----------------
        int stride = (gridDim.x - gemmBlocks) * 256;
        for (int e = (blockIdx.x - gemmBlocks) * 256 + threadIdx.x; e < E; e += stride) {
            int d = dst[e];
            col[rowptr[d] + rank[e]] = src[e];
        }
        return;
    }

    // ---------------- GEMM1 ----------------
    const int tid = threadIdx.x;
    const int lane = tid & 63;
    const int wid = tid >> 6;
    const int brow = blockIdx.x * 128;
    const int wr0 = (wid >> 1) * 64;
    const int wc0 = (wid & 1) * 64;
    const bool full = (brow + 128 <= N);

    f32x4 acc[4][4];
#pragma unroll
    for (int i = 0; i < 4; i++)
#pragma unroll
        for (int j = 0; j < 4; j++) acc[i][j] = (f32x4){0.f, 0.f, 0.f, 0.f};

    for (int kt = 0; kt < IN_DIM / 64; kt++) {
        const int k0 = kt * 64;
        // issue B first: global_load_lds streams while A-staging runs
#pragma unroll
        for (int p = 0; p < 4; p++) {
            int chunk = (wid * 4 + p) * 64 + lane;  // 16B chunk id
            int n = chunk >> 3;
            int kcs = chunk & 7;
            int kc = kcs ^ (n & 7);                 // inverse swizzle on source
            const unsigned short* srcp = &Wt[(size_t)n * IN_DIM + k0 + kc * 8];
            unsigned short* dstp = &Bs[(wid * 4 + p) * 512];  // wave-uniform base
            __builtin_amdgcn_global_load_lds(
                (const __attribute__((address_space(1))) u32*)(const void*)srcp,
                (__attribute__((address_space(3))) u32*)(void*)dstp, 16, 0, 0);
        }
        // stage A: 128 rows x 64 k, f32 -> bf16, reg-staged
#pragma unroll
        for (int p = 0; p < 4; p++) {
            int chunk = tid + p * 256;     // 1024 chunks of 8 elems
            int r = chunk >> 3;
            int kc = chunk & 7;
            const float* xp = &X[(size_t)(brow + r) * IN_DIM + k0 + kc * 8];
            float4 v0, v1;
            if (full || (brow + r) < N) {
                v0 = *(const float4*)xp;
                v1 = *(const float4*)(xp + 4);
            } else {
                v0 = make_float4(0.f, 0.f, 0.f, 0.f); v1 = v0;
            }
            u16x8 w;
            w[0] = f2bf(v0.x); w[1] = f2bf(v0.y); w[2] = f2bf(v0.z); w[3] = f2bf(v0.w);
            w[4] = f2bf(v1.x); w[5] = f2bf(v1.y); w[6] = f2bf(v1.z); w[7] = f2bf(v1.w);
            *(u16x8*)&As[elem_off(r, kc * 8)] = w;
        }
        __syncthreads();

#pragma unroll
        for (int kk = 0; kk < 2; kk++) {
            const int kel = kk * 32 + (lane >> 4) * 8;
            bf16x8 a[4], b[4];
#pragma unroll
            for (int mi = 0; mi < 4; mi++)
                a[mi] = *(const bf16x8*)&As[elem_off(wr0 + mi * 16 + (lane & 15), kel)];
#pragma unroll
            for (int ni = 0; ni < 4; ni++)
                b[ni] = *(const bf16x8*)&Bs[elem_off(wc0 + ni * 16 + (lane & 15), kel)];
#pragma unroll
            for (int mi = 0; mi < 4; mi++)
#pragma unroll
                for (int ni = 0; ni < 4; ni++)
                    acc[mi][ni] = __builtin_amdgcn_mfma_f32_16x16x32_bf16(
                        a[mi], b[ni], acc[mi][ni], 0, 0, 0);
        }
        __syncthreads();
    }

#pragma unroll
    for (int mi = 0; mi < 4; mi++) {
#pragma unroll
        for (int reg = 0; reg < 4; reg++) {
            int grow = brow + wr0 + mi * 16 + (lane >> 4) * 4 + reg;
            if (grow < N) {
#pragma unroll
                for (int ni = 0; ni < 4; ni++) {
                    int gcol = wc0 + ni * 16 + (lane & 15);
                    H[(size_t)grow * HD1 + gcol] = f2bf(acc[mi][ni][reg]);
                }
            }
        }
    }
}

// ---------- gather layer1: paired half-wave edges, weights from L2-resident dinv ----------
__global__ __launch_bounds__(256) void k_gather1(const unsigned short* __restrict__ h,
                                                 const int* __restrict__ rowptr,
                                                 const int* __restrict__ col,
                                                 const float* __restrict__ dinv,
                                                 const float* __restrict__ bias,
                                                 unsigned short* __restrict__ out, int N) {
    const int i = (blockIdx.x * 256 + threadIdx.x) >> 6;
    const int lane = threadIdx.x & 63;
    if (i >= N) return;
    const int half = lane >> 5;
    const int c4 = (lane & 31) * 4;           // my 4 columns
    const float di = dinv[i];
    const unsigned short* hc = h + c4;

    float a0 = 0.f, a1 = 0.f, a2 = 0.f, a3 = 0.f;
    if (half == 0) {  // self-loop term counted once
        uint2 sv = *(const uint2*)&hc[(size_t)i * HD1];
        float s = di * di;
        a0 = bf_lo(sv.x) * s; a1 = bf_hi(sv.x) * s;
        a2 = bf_lo(sv.y) * s; a3 = bf_hi(sv.y) * s;
    }
    const int beg = rowptr[i], end = rowptr[i + 1];
    for (int p0 = beg; p0 < end; p0 += 64) {
        int idx = p0 + lane;
        bool okl = idx < end;
        int myj = okl ? col[idx] : i;
        float mydj = okl ? dinv[myj] : 0.f;   // dinv: 200KB, L2-resident
        const int cnt8 = (min(64, end - p0) + 7) & ~7;
        uint2 v[4]; float wv[4];
#pragma unroll
        for (int q = 0; q < 4; q++) {          // prologue: edges 0..7
            int e = 2 * q + half;
            int j = __shfl(myj, e);
            wv[q] = __shfl(mydj, e) * di;
            v[q] = *(const uint2*)&hc[(size_t)j * HD1];
        }
        for (int k = 8; k < cnt8; k += 8) {
            uint2 nv[4]; float nw[4];
#pragma unroll
            for (int q = 0; q < 4; q++) {      // issue next 8 gathers first
                int e = k + 2 * q + half;
                int j = __shfl(myj, e);
                nw[q] = __shfl(mydj, e) * di;
                nv[q] = *(const uint2*)&hc[(size_t)j * HD1];
            }
#pragma unroll
            for (int q = 0; q < 4; q++) {      // consume previous 8
                a0 = fmaf(bf_lo(v[q].x), wv[q], a0);
                a1 = fmaf(bf_hi(v[q].x), wv[q], a1);
                a2 = fmaf(bf_lo(v[q].y), wv[q], a2);
                a3 = fmaf(bf_hi(v[q].y), wv[q], a3);
            }
#pragma unroll
            for (int q = 0; q < 4; q++) { v[q] = nv[q]; wv[q] = nw[q]; }
        }
#pragma unroll
        for (int q = 0; q < 4; q++) {
            a0 = fmaf(bf_lo(v[q].x), wv[q], a0);
            a1 = fmaf(bf_hi(v[q].x), wv[q], a1);
            a2 = fmaf(bf_lo(v[q].y), wv[q], a2);
            a3 = fmaf(bf_hi(v[q].y), wv[q], a3);
        }
    }
    // combine even/odd halves
    a0 += __shfl_xor(a0, 32);
    a1 += __shfl_xor(a1, 32);
    a2 += __shfl_xor(a2, 32);
    a3 += __shfl_xor(a3, 32);
    if (half == 0) {
        float4 bv = *(const float4*)&bias[c4];
        u32 w0 = (u32)f2bf(fmaxf(a0 + bv.x, 0.f)) | ((u32)f2bf(fmaxf(a1 + bv.y, 0.f)) << 16);
        u32 w1 = (u32)f2bf(fmaxf(a2 + bv.z, 0.f)) | ((u32)f2bf(fmaxf(a3 + bv.w, 0.f)) << 16);
        *(uint2*)&out[(size_t)i * HD1 + c4] = make_uint2(w0, w1);
    }
}

// ---------- GEMM2: agg1[N,128]bf16 @ Wt2[64][128]bf16 -> h2 [N,64]bf16, MFMA ----------
__global__ __launch_bounds__(256) void k_gemm2(const unsigned short* __restrict__ A,
                                               const unsigned short* __restrict__ Wt2,
                                               unsigned short* __restrict__ H, int N) {
    __shared__ unsigned short As[128 * 128];  // swizzled [row][k]
    __shared__ unsigned short Bs[64 * 128];   // swizzled [col][k]
    const int tid = threadIdx.x;
    const int lane = tid & 63;
    const int wid = tid >> 6;
    const int brow = blockIdx.x * 128;
    const int wr0 = wid * 32;

#pragma unroll
    for (int p = 0; p < 8; p++) {
        int chunk = (wid * 8 + p) * 64 + lane;
        int r = chunk >> 4;                 // 16 chunks per 128-elem row
        int kcs = chunk & 15;
        int kc = kcs ^ (r & 7);             // inverse swizzle on source
        const unsigned short* src = &A[(size_t)(brow + r) * HD1 + kc * 8];
        unsigned short* dst = &As[(wid * 8 + p) * 512];
        __builtin_amdgcn_global_load_lds(
            (const __attribute__((address_space(1))) u32*)(const void*)src,
            (__attribute__((address_space(3))) u32*)(void*)dst, 16, 0, 0);
    }
#pragma unroll
    for (int p = 0; p < 4; p++) {
        int chunk = (wid * 4 + p) * 64 + lane;
        int c = chunk >> 4;
        int kcs = chunk & 15;
        int kc = kcs ^ (c & 7);
        const unsigned short* src = &Wt2[(size_t)c * HD1 + kc * 8];
        unsigned short* dst = &Bs[(wid * 4 + p) * 512];
        __builtin_amdgcn_global_load_lds(
            (const __attribute__((address_space(1))) u32*)(const void*)src,
            (__attribute__((address_space(3))) u32*)(void*)dst, 16, 0, 0);
    }
    __syncthreads();

    f32x4 acc[2][4];
#pragma unroll
    for (int i = 0; i < 2; i++)
#pragma unroll
        for (int j = 0; j < 4; j++) acc[i][j] = (f32x4){0.f, 0.f, 0.f, 0.f};

#pragma unroll
    for (int kk = 0; kk < 4; kk++) {
        const int kel = kk * 32 + (lane >> 4) * 8;
        bf16x8 a[2], b[4];
#pragma unroll
        for (int mi = 0; mi < 2; mi++)
            a[mi] = *(const bf16x8*)&As[elem_off128(wr0 + mi * 16 + (lane & 15), kel)];
#pragma unroll
        for (int ni = 0; ni < 4; ni++)
            b[ni] = *(const bf16x8*)&Bs[elem_off128(ni * 16 + (lane & 15), kel)];
#pragma unroll
        for (int mi = 0; mi < 2; mi++)
#pragma unroll
            for (int ni = 0; ni < 4; ni++)
                acc[mi][ni] = __builtin_amdgcn_mfma_f32_16x16x32_bf16(
                    a[mi], b[ni], acc[mi][ni], 0, 0, 0);
    }

#pragma unroll
    for (int mi = 0; mi < 2; mi++) {
#pragma unroll
        for (int reg = 0; reg < 4; reg++) {
            int grow = brow + wr0 + mi * 16 + (lane >> 4) * 4 + reg;
            if (grow < N) {
#pragma unroll
                for (int ni = 0; ni < 4; ni++) {
                    int gcol = ni * 16 + (lane & 15);
                    H[(size_t)grow * HD2 + gcol] = f2bf(acc[mi][ni][reg]);
                }
            }
        }
    }
}

// ---------- gather layer2: paired half-wave edges, f32 out ----------
__global__ __launch_bounds__(256) void k_gather2(const unsigned short* __restrict__ h,
                                                 const int* __restrict__ rowptr,
                                                 const int* __restrict__ col,
                                                 const float* __restrict__ dinv,
                                                 const float* __restrict__ bias,
                                                 float* __restrict__ out, int N) {
    const int i = (blockIdx.x * 256 + threadIdx.x) >> 6;
    const int lane = threadIdx.x & 63;
    if (i >= N) return;
    const int half = lane >> 5;
    const int c2 = (lane & 31) * 2;           // my 2 columns
    const float di = dinv[i];
    const unsigned short* hc = h + c2;

    float a0 = 0.f, a1 = 0.f;
    if (half == 0) {
        u32 sv = *(const u32*)&hc[(size_t)i * HD2];
        float s = di * di;
        a0 = bf_lo(sv) * s; a1 = bf_hi(sv) * s;
    }
    const int beg = rowptr[i], end = rowptr[i + 1];
    for (int p0 = beg; p0 < end; p0 += 64) {
        int idx = p0 + lane;
        bool okl = idx < end;
        int myj = okl ? col[idx] : i;
        float mydj = okl ? dinv[myj] : 0.f;
        const int cnt8 = (min(64, end - p0) + 7) & ~7;
        u32 v[4]; float wv[4];
#pragma unroll
        for (int q = 0; q < 4; q++) {
            int e = 2 * q + half;
            int j = __shfl(myj, e);
            wv[q] = __shfl(mydj, e) * di;
            v[q] = *(const u32*)&hc[(size_t)j * HD2];
        }
        for (int k = 8; k < cnt8; k += 8) {
            u32 nv[4]; float nw[4];
#pragma unroll
            for (int q = 0; q < 4; q++) {
                int e = k + 2 * q + half;
                int j = __shfl(myj, e);
                nw[q] = __shfl(mydj, e) * di;
                nv[q] = *(const u32*)&hc[(size_t)j * HD2];
            }
#pragma unroll
            for (int q = 0; q < 4; q++) {
                a0 = fmaf(bf_lo(v[q]), wv[q], a0);
                a1 = fmaf(bf_hi(v[q]), wv[q], a1);
            }
#pragma unroll
            for (int q = 0; q < 4; q++) { v[q] = nv[q]; wv[q] = nw[q]; }
        }
#pragma unroll
        for (int q = 0; q < 4; q++) {
            a0 = fmaf(bf_lo(v[q]), wv[q], a0);
            a1 = fmaf(bf_hi(v[q]), wv[q], a1);
        }
    }
    a0 += __shfl_xor(a0, 32);
    a1 += __shfl_xor(a1, 32);
    if (half == 0) {
        float2 bv = *(const float2*)&bias[c2];
        float2 r = make_float2(fmaxf(a0 + bv.x, 0.f), fmaxf(a1 + bv.y, 0.f));
        *(float2*)&out[(size_t)i * HD2 + c2] = r;
    }
}

extern "C" void kernel_launch(void* const* d_in, const int* in_sizes, int n_in,
                              void* d_out, int out_size, void* d_ws, size_t ws_size,
                              hipStream_t stream) {
    const float* x  = (const float*)d_in[0];
    const int*   ei = (const int*)d_in[1];
    const float* W1 = (const float*)d_in[2];
    const float* b1 = (const float*)d_in[3];
    const float* W2 = (const float*)d_in[4];
    const float* b2 = (const float*)d_in[5];
    float* out = (float*)d_out;

    const int N = in_sizes[0] / IN_DIM;     // 50000
    const int E = in_sizes[1] / 2;          // 800000
    const int* src = ei;
    const int* dst = ei + E;

    // workspace layout (256B aligned)
    char* w = (char*)d_ws;
    size_t off = 0;
    auto alloc = [&](size_t bytes) -> void* {
        void* p = w + off;
        off = (off + bytes + 255) & ~(size_t)255;
        return p;
    };
    int*   deg    = (int*)alloc((size_t)N * 4);
    int*   rank   = (int*)alloc((size_t)E * 4);
    int*   rowptr = (int*)alloc((size_t)(N + 1) * 4);
    int*   bsum   = (int*)alloc(1024 * 4);
    int*   col    = (int*)alloc((size_t)E * 4);
    float* dinv   = (float*)alloc((size_t)N * 4);
    unsigned short* Wt  = (unsigned short*)alloc((size_t)IN_DIM * HD1 * 2);
    unsigned short* Wt2 = (unsigned short*)alloc((size_t)HD2 * HD1 * 2);
    unsigned short* h1  = (unsigned short*)alloc((size_t)N * HD1 * 2);          // bf16
    unsigned short* agg1= (unsigned short*)alloc((size_t)(N + 128) * HD1 * 2);  // bf16, padded
    unsigned short* h2  = h1;  // h1 dead after gather1; N*64*2 <= N*128*2

    hipMemsetAsync(deg, 0, (size_t)N * 4, stream);

    const int nb = (N + 255) / 256;          // 196 <= 256 (k_scan_final assumption)
    const int eb = (E + 255) / 256;
    const int gemmBlocks = (N + 127) / 128;  // 391
    const int fillBlocks = 512;

    k_prep<<<eb, 256, 0, stream>>>(dst, E, deg, rank, W1, Wt, W2, Wt2);
    k_dinv_bsum<<<nb, 256, 0, stream>>>(deg, N, dinv, bsum);
    k_scan_final<<<nb, 256, 0, stream>>>(deg, N, bsum, nb, rowptr);

    k_mega<<<gemmBlocks + fillBlocks, 256, 0, stream>>>(
        x, Wt, h1, N, gemmBlocks, src, dst, E, rowptr, rank, col);

    k_gather1<<<(N * 64 + 255) / 256, 256, 0, stream>>>(h1, rowptr, col, dinv, b1, agg1, N);
    k_gemm2<<<(N + 127) / 128, 256, 0, stream>>>(agg1, Wt2, h2, N);
    k_gather2<<<(N * 64 + 255) / 256, 256, 0, stream>>>(h2, rowptr, col, dinv, b2, out, N);
}